// Round 1
// baseline (3368.470 us; speedup 1.0000x reference)
//
#include <hip/hip_runtime.h>

// WalkerVisitLosses: N=M=8192, D=128, 10 labels.
// Restructure: walker needs aba[i,j] only for same-label pairs (block-diagonal
// after label sort). ba[k,j] = ab[j,k] * Rfac[j] * Ck[k] with
// Rfac[j]=Z_j*exp(m_j), Ck[k]=exp(-mu_k)/W_k, so only q=ab rows per label are
// materialized (<=1280 x 8192 fp32 = 40MB ws).
// Pipeline: bucket -> rowstats(x4 slices)+merge -> colstats+visit(x4)+merge
//           -> fill q -> per-label 64x64 Gram + fused log-reduction -> finish.

#define NROW 8192
#define NKEY 8192
#define DIM 128
#define NLAB 10
#define PMAX 1280
#define EPSf 1e-8f
#define SCALE 0.08838834764831845f /* 1/sqrt(128) */
#define SPLIT 4
#define KEYS_PER_SLICE 2048

// workspace byte offsets (total ~42.8 MB)
#define WS_WA 0
#define WS_VA 8
#define WS_CNT 64
#define WS_OFF 128
#define WS_SIDX 256
#define WS_M 33024
#define WS_IZ 65792
#define WS_CV 98560
#define WS_RF 131328
#define WS_CK 164096
#define WS_PM4 196864
#define WS_PS4 327936
#define WS_PMC4 459008
#define WS_PSC4 590080
#define WS_PVC4 721152
#define WS_P 852224

__global__ __launch_bounds__(256) void k_bucket(const int* __restrict__ lab,
                                                int* cnt, int* offs, int* sidx,
                                                double* wa, double* va) {
  __shared__ int lc[NLAB], lcur[NLAB];
  int tid = threadIdx.x;
  if (tid < NLAB) lc[tid] = 0;
  __syncthreads();
  for (int i = tid; i < NROW; i += 256) {
    int l = lab[i]; l = l < 0 ? 0 : (l > 9 ? 9 : l);
    atomicAdd(&lc[l], 1);
  }
  __syncthreads();
  if (tid == 0) {
    int run = 0;
    for (int l = 0; l < NLAB; ++l) { cnt[l] = lc[l]; offs[l] = run; lcur[l] = run; run += lc[l]; }
    *wa = 0.0; *va = 0.0;
  }
  __syncthreads();
  for (int i = tid; i < NROW; i += 256) {
    int l = lab[i]; l = l < 0 ? 0 : (l > 9 ? 9 : l);
    int p = atomicAdd(&lcur[l], 1);
    sidx[p] = i;
  }
}

// Row stats over p = a.b^T*SCALE : per-slice online (max,sumexp) partials.
__global__ __launch_bounds__(256) void k_rowstats(const float* __restrict__ A,
                                                  const float* __restrict__ B,
                                                  float* __restrict__ pm4,
                                                  float* __restrict__ ps4) {
  __shared__ __align__(16) float qa[64][132];
  __shared__ __align__(16) float kb[64][132];
  __shared__ float pm[64][16];
  __shared__ float ps[64][16];
  int tid = threadIdx.x;
  int r0 = blockIdx.x * 64;
  int slice = blockIdx.y;
#pragma unroll
  for (int t = 0; t < 8; ++t) {
    int idx = tid + t * 256, row = idx >> 5, q4 = idx & 31;
    *(float4*)&qa[row][q4 * 4] = *(const float4*)&A[(r0 + row) * DIM + q4 * 4];
  }
  int ty = tid >> 4, tx = tid & 15;
  float tmax[4], tsum[4];
#pragma unroll
  for (int r = 0; r < 4; ++r) { tmax[r] = -1e30f; tsum[r] = 0.f; }
  for (int t = 0; t < 32; ++t) {
    int c0 = slice * KEYS_PER_SLICE + t * 64;
    __syncthreads();
#pragma unroll
    for (int u = 0; u < 8; ++u) {
      int idx = tid + u * 256, row = idx >> 5, q4 = idx & 31;
      *(float4*)&kb[row][q4 * 4] = *(const float4*)&B[(c0 + row) * DIM + q4 * 4];
    }
    __syncthreads();
    float acc[4][4];
#pragma unroll
    for (int r = 0; r < 4; ++r)
#pragma unroll
      for (int s = 0; s < 4; ++s) acc[r][s] = 0.f;
#pragma unroll 4
    for (int d4 = 0; d4 < 32; ++d4) {
      float4 av[4], bv[4];
#pragma unroll
      for (int r = 0; r < 4; ++r) av[r] = *(float4*)&qa[4 * ty + r][d4 * 4];
#pragma unroll
      for (int s = 0; s < 4; ++s) bv[s] = *(float4*)&kb[tx + 16 * s][d4 * 4];
#pragma unroll
      for (int r = 0; r < 4; ++r)
#pragma unroll
        for (int s = 0; s < 4; ++s) {
          acc[r][s] = fmaf(av[r].x, bv[s].x, acc[r][s]);
          acc[r][s] = fmaf(av[r].y, bv[s].y, acc[r][s]);
          acc[r][s] = fmaf(av[r].z, bv[s].z, acc[r][s]);
          acc[r][s] = fmaf(av[r].w, bv[s].w, acc[r][s]);
        }
    }
#pragma unroll
    for (int r = 0; r < 4; ++r)
#pragma unroll
      for (int s = 0; s < 4; ++s) {
        float v = acc[r][s] * SCALE;
        float nm = fmaxf(tmax[r], v);
        tsum[r] = tsum[r] * __expf(tmax[r] - nm) + __expf(v - nm);
        tmax[r] = nm;
      }
  }
  __syncthreads();
#pragma unroll
  for (int r = 0; r < 4; ++r) { pm[4 * ty + r][tx] = tmax[r]; ps[4 * ty + r][tx] = tsum[r]; }
  __syncthreads();
  if (tid < 64) {
    float mm = -1e30f;
    for (int t = 0; t < 16; ++t) mm = fmaxf(mm, pm[tid][t]);
    float zz = 0.f;
    for (int t = 0; t < 16; ++t) zz += ps[tid][t] * __expf(pm[tid][t] - mm);
    pm4[slice * NROW + r0 + tid] = mm;
    ps4[slice * NROW + r0 + tid] = zz;
  }
}

__global__ __launch_bounds__(256) void k_merge_row(const float* __restrict__ pm4,
                                                   const float* __restrict__ ps4,
                                                   float* Mo, float* iZ, float* cv,
                                                   float* rf) {
  int i = blockIdx.x * 256 + threadIdx.x;
  float m = -1e30f;
#pragma unroll
  for (int s = 0; s < SPLIT; ++s) m = fmaxf(m, pm4[s * NROW + i]);
  float z = 0.f;
#pragma unroll
  for (int s = 0; s < SPLIT; ++s) z += ps4[s * NROW + i] * __expf(pm4[s * NROW + i] - m);
  Mo[i] = m;
  iZ[i] = 1.f / z;
  cv[i] = __expf(-m) / z;
  rf[i] = z * __expf(m);
}

// Column stats of p (rows of p^T) + visit accumulation v_k = sum_j ab[j,k].
__global__ __launch_bounds__(256) void k_colstats(const float* __restrict__ Bm,
                                                  const float* __restrict__ Am,
                                                  const float* __restrict__ cv,
                                                  float* __restrict__ pmc4,
                                                  float* __restrict__ psc4,
                                                  float* __restrict__ pvc4) {
  __shared__ __align__(16) float qa[64][132];
  __shared__ __align__(16) float kb[64][132];
  __shared__ float cvs[64];
  __shared__ float pm[64][16];
  __shared__ float ps[64][16];
  __shared__ float pv[64][16];
  int tid = threadIdx.x;
  int r0 = blockIdx.x * 64;  // column block (= b rows)
  int slice = blockIdx.y;
#pragma unroll
  for (int t = 0; t < 8; ++t) {
    int idx = tid + t * 256, row = idx >> 5, q4 = idx & 31;
    *(float4*)&qa[row][q4 * 4] = *(const float4*)&Bm[(r0 + row) * DIM + q4 * 4];
  }
  int ty = tid >> 4, tx = tid & 15;
  float tmax[4], tsum[4], tv[4];
#pragma unroll
  for (int r = 0; r < 4; ++r) { tmax[r] = -1e30f; tsum[r] = 0.f; tv[r] = 0.f; }
  for (int t = 0; t < 32; ++t) {
    int c0 = slice * KEYS_PER_SLICE + t * 64;
    __syncthreads();
#pragma unroll
    for (int u = 0; u < 8; ++u) {
      int idx = tid + u * 256, row = idx >> 5, q4 = idx & 31;
      *(float4*)&kb[row][q4 * 4] = *(const float4*)&Am[(c0 + row) * DIM + q4 * 4];
    }
    if (tid < 64) cvs[tid] = cv[c0 + tid];
    __syncthreads();
    float acc[4][4];
#pragma unroll
    for (int r = 0; r < 4; ++r)
#pragma unroll
      for (int s = 0; s < 4; ++s) acc[r][s] = 0.f;
#pragma unroll 4
    for (int d4 = 0; d4 < 32; ++d4) {
      float4 av[4], bv[4];
#pragma unroll
      for (int r = 0; r < 4; ++r) av[r] = *(float4*)&qa[4 * ty + r][d4 * 4];
#pragma unroll
      for (int s = 0; s < 4; ++s) bv[s] = *(float4*)&kb[tx + 16 * s][d4 * 4];
#pragma unroll
      for (int r = 0; r < 4; ++r)
#pragma unroll
        for (int s = 0; s < 4; ++s) {
          acc[r][s] = fmaf(av[r].x, bv[s].x, acc[r][s]);
          acc[r][s] = fmaf(av[r].y, bv[s].y, acc[r][s]);
          acc[r][s] = fmaf(av[r].z, bv[s].z, acc[r][s]);
          acc[r][s] = fmaf(av[r].w, bv[s].w, acc[r][s]);
        }
    }
#pragma unroll
    for (int r = 0; r < 4; ++r)
#pragma unroll
      for (int s = 0; s < 4; ++s) {
        float v = acc[r][s] * SCALE;
        float nm = fmaxf(tmax[r], v);
        tsum[r] = tsum[r] * __expf(tmax[r] - nm) + __expf(v - nm);
        tmax[r] = nm;
        tv[r] += __expf(v) * cvs[tx + 16 * s];
      }
  }
  __syncthreads();
#pragma unroll
  for (int r = 0; r < 4; ++r) {
    pm[4 * ty + r][tx] = tmax[r];
    ps[4 * ty + r][tx] = tsum[r];
    pv[4 * ty + r][tx] = tv[r];
  }
  __syncthreads();
  if (tid < 64) {
    float mm = -1e30f;
    for (int t = 0; t < 16; ++t) mm = fmaxf(mm, pm[tid][t]);
    float ww = 0.f, vv = 0.f;
    for (int t = 0; t < 16; ++t) {
      ww += ps[tid][t] * __expf(pm[tid][t] - mm);
      vv += pv[tid][t];
    }
    pmc4[slice * NROW + r0 + tid] = mm;
    psc4[slice * NROW + r0 + tid] = ww;
    pvc4[slice * NROW + r0 + tid] = vv;
  }
}

__global__ __launch_bounds__(256) void k_merge_col(const float* __restrict__ pmc4,
                                                   const float* __restrict__ psc4,
                                                   const float* __restrict__ pvc4,
                                                   float* ck, double* va) {
  __shared__ float red[4];
  int tid = threadIdx.x;
  int i = blockIdx.x * 256 + tid;
  float m = -1e30f;
#pragma unroll
  for (int s = 0; s < SPLIT; ++s) m = fmaxf(m, pmc4[s * NROW + i]);
  float w = 0.f, vk = 0.f;
#pragma unroll
  for (int s = 0; s < SPLIT; ++s) {
    w += psc4[s * NROW + i] * __expf(pmc4[s * NROW + i] - m);
    vk += pvc4[s * NROW + i];
  }
  ck[i] = __expf(-m) / w;
  float lsum = __logf(EPSf + vk * (1.f / 8192.f));
  for (int o = 32; o; o >>= 1) lsum += __shfl_down(lsum, o);
  if ((tid & 63) == 0) red[tid >> 6] = lsum;
  __syncthreads();
  if (tid == 0) {
    double tot = (double)red[0] + (double)red[1] + (double)red[2] + (double)red[3];
    atomicAdd(va, -tot / 8192.0);
  }
}

// Materialize q = ab rows for one label (sorted gather), zero-padded to 64.
__global__ __launch_bounds__(256) void k_fill(const float* __restrict__ A,
                                              const float* __restrict__ B,
                                              const int* __restrict__ sidx,
                                              const int* __restrict__ cnt,
                                              const int* __restrict__ offs,
                                              const float* __restrict__ Mo,
                                              const float* __restrict__ iZ,
                                              float* __restrict__ P) {
  int lab = blockIdx.z, c = cnt[lab], o = offs[lab];
  int r0 = blockIdx.x * 64;
  if (r0 >= ((c + 63) & ~63)) return;
  int slice = blockIdx.y;
  __shared__ __align__(16) float qa[64][132];
  __shared__ __align__(16) float kb[64][132];
  __shared__ int gidx[64];
  __shared__ float mrow[64], izrow[64];
  int tid = threadIdx.x;
  if (tid < 64) {
    int rr = r0 + tid;
    int gi = (rr < c) ? sidx[o + rr] : 0;
    gidx[tid] = gi;
    mrow[tid] = Mo[gi];
    izrow[tid] = iZ[gi];
  }
  __syncthreads();
#pragma unroll
  for (int t = 0; t < 8; ++t) {
    int idx = tid + t * 256, row = idx >> 5, q4 = idx & 31;
    *(float4*)&qa[row][q4 * 4] = *(const float4*)&A[gidx[row] * DIM + q4 * 4];
  }
  int ty = tid >> 4, tx = tid & 15;
  for (int t = 0; t < 32; ++t) {
    int c0 = slice * KEYS_PER_SLICE + t * 64;
    __syncthreads();
#pragma unroll
    for (int u = 0; u < 8; ++u) {
      int idx = tid + u * 256, row = idx >> 5, q4 = idx & 31;
      *(float4*)&kb[row][q4 * 4] = *(const float4*)&B[(c0 + row) * DIM + q4 * 4];
    }
    __syncthreads();
    float acc[4][4];
#pragma unroll
    for (int r = 0; r < 4; ++r)
#pragma unroll
      for (int s = 0; s < 4; ++s) acc[r][s] = 0.f;
#pragma unroll 4
    for (int d4 = 0; d4 < 32; ++d4) {
      float4 av[4], bv[4];
#pragma unroll
      for (int r = 0; r < 4; ++r) av[r] = *(float4*)&qa[4 * ty + r][d4 * 4];
#pragma unroll
      for (int s = 0; s < 4; ++s) bv[s] = *(float4*)&kb[tx + 16 * s][d4 * 4];
#pragma unroll
      for (int r = 0; r < 4; ++r)
#pragma unroll
        for (int s = 0; s < 4; ++s) {
          acc[r][s] = fmaf(av[r].x, bv[s].x, acc[r][s]);
          acc[r][s] = fmaf(av[r].y, bv[s].y, acc[r][s]);
          acc[r][s] = fmaf(av[r].z, bv[s].z, acc[r][s]);
          acc[r][s] = fmaf(av[r].w, bv[s].w, acc[r][s]);
        }
    }
#pragma unroll
    for (int r = 0; r < 4; ++r)
#pragma unroll
      for (int s = 0; s < 4; ++s) {
        int row = 4 * ty + r;
        int rr = r0 + row;
        int k = c0 + tx + 16 * s;
        float qv = (rr < c) ? __expf(acc[r][s] * SCALE - mrow[row]) * izrow[row] : 0.f;
        P[rr * NKEY + k] = qv;
      }
  }
}

// Per-label Gram G = Q (Q*Rfac*Ck)^T, fused -log(eps+G) reduction.
__global__ __launch_bounds__(256) void k_gram(const float* __restrict__ P,
                                              const int* __restrict__ sidx,
                                              const int* __restrict__ cnt,
                                              const int* __restrict__ offs,
                                              const float* __restrict__ rf,
                                              const float* __restrict__ ck,
                                              double* wa) {
  int lab = blockIdx.z, c = cnt[lab], o = offs[lab];
  int i0 = blockIdx.y * 64, j0 = blockIdx.x * 64;
  if (i0 >= c || j0 >= c) return;
  __shared__ __align__(16) float Qs[64][68];
  __shared__ __align__(16) float Rs[64][68];
  __shared__ float rfj[64];
  __shared__ float red[4];
  int tid = threadIdx.x;
  if (tid < 64) {
    int jj = j0 + tid;
    rfj[tid] = (jj < c) ? rf[sidx[o + jj]] : 0.f;
  }
  int ty = tid >> 4, tx = tid & 15;
  float acc[4][4];
#pragma unroll
  for (int r = 0; r < 4; ++r)
#pragma unroll
    for (int s = 0; s < 4; ++s) acc[r][s] = 0.f;
  for (int k0 = 0; k0 < NKEY; k0 += 64) {
    __syncthreads();
#pragma unroll
    for (int t = 0; t < 4; ++t) {
      int idx = tid + t * 256, row = idx >> 4, q4 = idx & 15;
      float4 qv = *(const float4*)&P[(i0 + row) * NKEY + k0 + q4 * 4];
      float4 rv = *(const float4*)&P[(j0 + row) * NKEY + k0 + q4 * 4];
      float4 cc = *(const float4*)&ck[k0 + q4 * 4];
      float rfv = rfj[row];
      int kk = q4 * 4;
      Qs[kk + 0][row] = qv.x; Qs[kk + 1][row] = qv.y;
      Qs[kk + 2][row] = qv.z; Qs[kk + 3][row] = qv.w;
      Rs[kk + 0][row] = rv.x * cc.x * rfv; Rs[kk + 1][row] = rv.y * cc.y * rfv;
      Rs[kk + 2][row] = rv.z * cc.z * rfv; Rs[kk + 3][row] = rv.w * cc.w * rfv;
    }
    __syncthreads();
#pragma unroll 8
    for (int kk = 0; kk < 64; ++kk) {
      float4 qv = *(float4*)&Qs[kk][4 * ty];
      float4 rv = *(float4*)&Rs[kk][4 * tx];
      acc[0][0] = fmaf(qv.x, rv.x, acc[0][0]);
      acc[0][1] = fmaf(qv.x, rv.y, acc[0][1]);
      acc[0][2] = fmaf(qv.x, rv.z, acc[0][2]);
      acc[0][3] = fmaf(qv.x, rv.w, acc[0][3]);
      acc[1][0] = fmaf(qv.y, rv.x, acc[1][0]);
      acc[1][1] = fmaf(qv.y, rv.y, acc[1][1]);
      acc[1][2] = fmaf(qv.y, rv.z, acc[1][2]);
      acc[1][3] = fmaf(qv.y, rv.w, acc[1][3]);
      acc[2][0] = fmaf(qv.z, rv.x, acc[2][0]);
      acc[2][1] = fmaf(qv.z, rv.y, acc[2][1]);
      acc[2][2] = fmaf(qv.z, rv.z, acc[2][2]);
      acc[2][3] = fmaf(qv.z, rv.w, acc[2][3]);
      acc[3][0] = fmaf(qv.w, rv.x, acc[3][0]);
      acc[3][1] = fmaf(qv.w, rv.y, acc[3][1]);
      acc[3][2] = fmaf(qv.w, rv.z, acc[3][2]);
      acc[3][3] = fmaf(qv.w, rv.w, acc[3][3]);
    }
  }
  float lsum = 0.f;
#pragma unroll
  for (int r = 0; r < 4; ++r)
#pragma unroll
    for (int s = 0; s < 4; ++s) {
      int i = i0 + 4 * ty + r, j = j0 + 4 * tx + s;
      if (i < c && j < c) lsum += __logf(EPSf + acc[r][s]);
    }
  for (int o2 = 32; o2; o2 >>= 1) lsum += __shfl_down(lsum, o2);
  __syncthreads();
  if ((tid & 63) == 0) red[tid >> 6] = lsum;
  __syncthreads();
  if (tid == 0) {
    double tot = (double)red[0] + (double)red[1] + (double)red[2] + (double)red[3];
    atomicAdd(wa, -tot / ((double)NROW * (double)c));
  }
}

__global__ void k_finish(const double* wa, const double* va, float* out) {
  out[0] = (float)(*wa);
  out[1] = (float)(*va);
}

extern "C" void kernel_launch(void* const* d_in, const int* in_sizes, int n_in,
                              void* d_out, int out_size, void* d_ws, size_t ws_size,
                              hipStream_t stream) {
  const float* A = (const float*)d_in[0];
  const float* B = (const float*)d_in[1];
  const int* LAB = (const int*)d_in[2];
  float* out = (float*)d_out;
  char* w = (char*)d_ws;
  double* WA = (double*)(w + WS_WA);
  double* VA = (double*)(w + WS_VA);
  int* CNT = (int*)(w + WS_CNT);
  int* OFFS = (int*)(w + WS_OFF);
  int* SIDX = (int*)(w + WS_SIDX);
  float* Mrow = (float*)(w + WS_M);
  float* IZ = (float*)(w + WS_IZ);
  float* CV = (float*)(w + WS_CV);
  float* RF = (float*)(w + WS_RF);
  float* CK = (float*)(w + WS_CK);
  float* PM4 = (float*)(w + WS_PM4);
  float* PS4 = (float*)(w + WS_PS4);
  float* PMC4 = (float*)(w + WS_PMC4);
  float* PSC4 = (float*)(w + WS_PSC4);
  float* PVC4 = (float*)(w + WS_PVC4);
  float* P = (float*)(w + WS_P);

  k_bucket<<<1, 256, 0, stream>>>(LAB, CNT, OFFS, SIDX, WA, VA);
  k_rowstats<<<dim3(128, SPLIT), 256, 0, stream>>>(A, B, PM4, PS4);
  k_merge_row<<<32, 256, 0, stream>>>(PM4, PS4, Mrow, IZ, CV, RF);
  k_colstats<<<dim3(128, SPLIT), 256, 0, stream>>>(B, A, CV, PMC4, PSC4, PVC4);
  k_merge_col<<<32, 256, 0, stream>>>(PMC4, PSC4, PVC4, CK, VA);
  k_fill<<<dim3(20, SPLIT, NLAB), 256, 0, stream>>>(A, B, SIDX, CNT, OFFS, Mrow, IZ, P);
  k_gram<<<dim3(20, 20, NLAB), 256, 0, stream>>>(P, SIDX, CNT, OFFS, RF, CK, WA);
  k_finish<<<1, 1, 0, stream>>>(WA, VA, out);
}

// Round 2
// 466.742 us; speedup vs baseline: 7.2170x; 7.2170x over previous
//
#include <hip/hip_runtime.h>

// WalkerVisitLosses, round 2: full bf16-MFMA restructure.
// p = a.b^T/sqrt(128); no-max softmax (exp(p) can't overflow for N(0,1) data):
//   SE_i = sum_k exp(p_ik)         (row sumexp)   ab[i,k] = exp(p_ik)/SE_i
//   CS_k = sum_j exp(p_jk)         (col sumexp)   ck_k = 1/CS_k
//   ba[k,j] = exp(p_jk)*ck_k
// walker needs aba only on same-label pairs: sort rows by label, materialize
// P[p,k] = ab[sidx[p],k] in bf16 (134 MB, unique rows -> no round-1 race),
// G[i,j] = SE_j * sum_k P_ik * (P_jk * ck_k)  per label via bf16 MFMA.
// visit_k = sum_i ab[i,k] = sum_i exp(p_ik)/SE_i accumulated in colstats.

typedef __attribute__((ext_vector_type(8))) short bf16x8;
typedef __attribute__((ext_vector_type(4))) float f32x4;

#define NROW 8192
#define DIM 128
#define NLAB 10
#define EPSf 1e-8f
#define SCALE 0.08838834764831845f /* 1/sqrt(128) */

// workspace byte offsets (total ~142.6 MB; round-1 used 269 MB OK)
#define O_WA 0
#define O_VA 8
#define O_CNT 64
#define O_OFF 128
#define O_SIDX 256
#define O_SE 65536
#define O_CV 98304
#define O_CK 131072
#define O_PS 163840
#define O_PC 688128
#define O_PV 1212416
#define O_ABF 1736704
#define O_BBF 3833856
#define O_P 8388608

__device__ __forceinline__ unsigned short f2bf(float f) {
  unsigned u = __builtin_bit_cast(unsigned, f);
  u += 0x7fffu + ((u >> 16) & 1u);
  return (unsigned short)(u >> 16);
}
__device__ __forceinline__ float bf2f(short s) {
  unsigned u = ((unsigned)(unsigned short)s) << 16;
  return __builtin_bit_cast(float, u);
}

__global__ __launch_bounds__(256) void k_bucket(const int* __restrict__ lab,
                                                int* cnt, int* offs, int* sidx,
                                                double* wa, double* va) {
  __shared__ int lc[NLAB], lcur[NLAB];
  int tid = threadIdx.x;
  if (tid < NLAB) lc[tid] = 0;
  __syncthreads();
  for (int i = tid; i < NROW; i += 256) {
    int l = lab[i]; l = l < 0 ? 0 : (l > 9 ? 9 : l);
    atomicAdd(&lc[l], 1);
  }
  __syncthreads();
  if (tid == 0) {
    int run = 0;
    for (int l = 0; l < NLAB; ++l) { cnt[l] = lc[l]; offs[l] = run; lcur[l] = run; run += lc[l]; }
    *wa = 0.0; *va = 0.0;
  }
  __syncthreads();
  for (int i = tid; i < NROW; i += 256) {
    int l = lab[i]; l = l < 0 ? 0 : (l > 9 ? 9 : l);
    int p = atomicAdd(&lcur[l], 1);
    sidx[p] = i;
  }
}

__global__ __launch_bounds__(256) void k_convert(const float* __restrict__ X,
                                                 unsigned short* __restrict__ Y) {
  int i = (blockIdx.x * 256 + threadIdx.x) * 8;
  f32x4 a = *(const f32x4*)(X + i);
  f32x4 b = *(const f32x4*)(X + i + 4);
  bf16x8 o;
  o[0] = (short)f2bf(a[0]); o[1] = (short)f2bf(a[1]);
  o[2] = (short)f2bf(a[2]); o[3] = (short)f2bf(a[3]);
  o[4] = (short)f2bf(b[0]); o[5] = (short)f2bf(b[1]);
  o[6] = (short)f2bf(b[2]); o[7] = (short)f2bf(b[3]);
  *(bf16x8*)(Y + i) = o;
}

// Row sum-of-exp over p. Block: 128 rows x 1024 cols (8 tiles of 128).
// 4 waves in 2x2; fragments register-resident, no LDS.
__global__ __launch_bounds__(256, 2) void k_rowstats(const unsigned short* __restrict__ Abf,
                                                     const unsigned short* __restrict__ Bbf,
                                                     float* __restrict__ ps) {
  int tid = threadIdx.x;
  int wave = tid >> 6, lane = tid & 63;
  int wrow = wave >> 1, wcol = wave & 1;
  int m = lane & 15, quad = lane >> 4;
  int r0 = blockIdx.x * 128 + wrow * 64;
  bf16x8 af[4][4];
#pragma unroll
  for (int mi = 0; mi < 4; ++mi)
#pragma unroll
    for (int ks = 0; ks < 4; ++ks)
      af[mi][ks] = *(const bf16x8*)(Abf + (r0 + mi * 16 + m) * DIM + ks * 32 + quad * 8);
  float tsum[4][4];
#pragma unroll
  for (int mi = 0; mi < 4; ++mi)
#pragma unroll
    for (int r = 0; r < 4; ++r) tsum[mi][r] = 0.f;
  for (int t = 0; t < 8; ++t) {
    int c0 = blockIdx.y * 1024 + t * 128 + wcol * 64;
    bf16x8 bf[4][4];
#pragma unroll
    for (int ni = 0; ni < 4; ++ni)
#pragma unroll
      for (int ks = 0; ks < 4; ++ks)
        bf[ni][ks] = *(const bf16x8*)(Bbf + (c0 + ni * 16 + m) * DIM + ks * 32 + quad * 8);
    f32x4 acc[4][4];
#pragma unroll
    for (int mi = 0; mi < 4; ++mi)
#pragma unroll
      for (int ni = 0; ni < 4; ++ni) acc[mi][ni] = (f32x4){0.f, 0.f, 0.f, 0.f};
#pragma unroll
    for (int ks = 0; ks < 4; ++ks)
#pragma unroll
      for (int mi = 0; mi < 4; ++mi)
#pragma unroll
        for (int ni = 0; ni < 4; ++ni)
          acc[mi][ni] = __builtin_amdgcn_mfma_f32_16x16x32_bf16(af[mi][ks], bf[ni][ks], acc[mi][ni], 0, 0, 0);
#pragma unroll
    for (int mi = 0; mi < 4; ++mi)
#pragma unroll
      for (int ni = 0; ni < 4; ++ni)
#pragma unroll
        for (int r = 0; r < 4; ++r)
          tsum[mi][r] += __expf(acc[mi][ni][r] * SCALE);
  }
#pragma unroll
  for (int off = 1; off < 16; off <<= 1)
#pragma unroll
    for (int mi = 0; mi < 4; ++mi)
#pragma unroll
      for (int r = 0; r < 4; ++r) tsum[mi][r] += __shfl_xor(tsum[mi][r], off);
  if (m == 0) {
#pragma unroll
    for (int mi = 0; mi < 4; ++mi)
#pragma unroll
      for (int r = 0; r < 4; ++r)
        ps[(blockIdx.y * 2 + wcol) * NROW + r0 + mi * 16 + quad * 4 + r] = tsum[mi][r];
  }
}

__global__ __launch_bounds__(256) void k_merge_row(const float* __restrict__ ps,
                                                   float* __restrict__ SE,
                                                   float* __restrict__ CV) {
  int i = blockIdx.x * 256 + threadIdx.x;
  float s = 0.f;
#pragma unroll
  for (int t = 0; t < 16; ++t) s += ps[t * NROW + i];
  SE[i] = s;
  CV[i] = 1.f / s;
}

// Column sum-of-exp (rows of p^T = b-rows) + visit accumulation.
__global__ __launch_bounds__(256, 2) void k_colstats(const unsigned short* __restrict__ Bbf,
                                                     const unsigned short* __restrict__ Abf,
                                                     const float* __restrict__ CV,
                                                     float* __restrict__ pc,
                                                     float* __restrict__ pv) {
  int tid = threadIdx.x;
  int wave = tid >> 6, lane = tid & 63;
  int wrow = wave >> 1, wcol = wave & 1;
  int m = lane & 15, quad = lane >> 4;
  int r0 = blockIdx.x * 128 + wrow * 64;  // k rows
  bf16x8 af[4][4];
#pragma unroll
  for (int mi = 0; mi < 4; ++mi)
#pragma unroll
    for (int ks = 0; ks < 4; ++ks)
      af[mi][ks] = *(const bf16x8*)(Bbf + (r0 + mi * 16 + m) * DIM + ks * 32 + quad * 8);
  float tsum[4][4], tvis[4][4];
#pragma unroll
  for (int mi = 0; mi < 4; ++mi)
#pragma unroll
    for (int r = 0; r < 4; ++r) { tsum[mi][r] = 0.f; tvis[mi][r] = 0.f; }
  for (int t = 0; t < 8; ++t) {
    int c0 = blockIdx.y * 1024 + t * 128 + wcol * 64;  // j cols (a rows)
    bf16x8 bf[4][4];
    float cvv[4];
#pragma unroll
    for (int ni = 0; ni < 4; ++ni) {
      cvv[ni] = CV[c0 + ni * 16 + m];
#pragma unroll
      for (int ks = 0; ks < 4; ++ks)
        bf[ni][ks] = *(const bf16x8*)(Abf + (c0 + ni * 16 + m) * DIM + ks * 32 + quad * 8);
    }
    f32x4 acc[4][4];
#pragma unroll
    for (int mi = 0; mi < 4; ++mi)
#pragma unroll
      for (int ni = 0; ni < 4; ++ni) acc[mi][ni] = (f32x4){0.f, 0.f, 0.f, 0.f};
#pragma unroll
    for (int ks = 0; ks < 4; ++ks)
#pragma unroll
      for (int mi = 0; mi < 4; ++mi)
#pragma unroll
        for (int ni = 0; ni < 4; ++ni)
          acc[mi][ni] = __builtin_amdgcn_mfma_f32_16x16x32_bf16(af[mi][ks], bf[ni][ks], acc[mi][ni], 0, 0, 0);
#pragma unroll
    for (int mi = 0; mi < 4; ++mi)
#pragma unroll
      for (int ni = 0; ni < 4; ++ni)
#pragma unroll
        for (int r = 0; r < 4; ++r) {
          float e = __expf(acc[mi][ni][r] * SCALE);
          tsum[mi][r] += e;
          tvis[mi][r] = fmaf(e, cvv[ni], tvis[mi][r]);
        }
  }
#pragma unroll
  for (int off = 1; off < 16; off <<= 1)
#pragma unroll
    for (int mi = 0; mi < 4; ++mi)
#pragma unroll
      for (int r = 0; r < 4; ++r) {
        tsum[mi][r] += __shfl_xor(tsum[mi][r], off);
        tvis[mi][r] += __shfl_xor(tvis[mi][r], off);
      }
  if (m == 0) {
#pragma unroll
    for (int mi = 0; mi < 4; ++mi)
#pragma unroll
      for (int r = 0; r < 4; ++r) {
        int k = r0 + mi * 16 + quad * 4 + r;
        pc[(blockIdx.y * 2 + wcol) * NROW + k] = tsum[mi][r];
        pv[(blockIdx.y * 2 + wcol) * NROW + k] = tvis[mi][r];
      }
  }
}

__global__ __launch_bounds__(256) void k_merge_col(const float* __restrict__ pc,
                                                   const float* __restrict__ pv,
                                                   float* __restrict__ CK, double* va) {
  __shared__ float red[4];
  int tid = threadIdx.x;
  int i = blockIdx.x * 256 + tid;
  float s = 0.f, v = 0.f;
#pragma unroll
  for (int t = 0; t < 16; ++t) { s += pc[t * NROW + i]; v += pv[t * NROW + i]; }
  CK[i] = 1.f / s;
  float l = __logf(EPSf + v * (1.f / 8192.f));
#pragma unroll
  for (int off = 32; off; off >>= 1) l += __shfl_down(l, off);
  if ((tid & 63) == 0) red[tid >> 6] = l;
  __syncthreads();
  if (tid == 0) {
    double tot = (double)red[0] + (double)red[1] + (double)red[2] + (double)red[3];
    atomicAdd(va, -tot / 8192.0);
  }
}

// P[p,k] = exp(p_{sidx[p],k}) / SE  in bf16, rows in label-sorted order.
__global__ __launch_bounds__(256, 2) void k_fill(const unsigned short* __restrict__ Abf,
                                                 const unsigned short* __restrict__ Bbf,
                                                 const int* __restrict__ sidx,
                                                 const float* __restrict__ CV,
                                                 unsigned short* __restrict__ P) {
  __shared__ int gidx[128];
  __shared__ float rinv[128];
  int tid = threadIdx.x;
  if (tid < 128) {
    int gi = sidx[blockIdx.x * 128 + tid];
    gidx[tid] = gi;
    rinv[tid] = CV[gi];
  }
  __syncthreads();
  int wave = tid >> 6, lane = tid & 63;
  int wrow = wave >> 1, wcol = wave & 1;
  int m = lane & 15, quad = lane >> 4;
  bf16x8 af[4][4];
  float rv[4][4];
#pragma unroll
  for (int mi = 0; mi < 4; ++mi) {
    int gi = gidx[wrow * 64 + mi * 16 + m];
#pragma unroll
    for (int ks = 0; ks < 4; ++ks)
      af[mi][ks] = *(const bf16x8*)(Abf + gi * DIM + ks * 32 + quad * 8);
#pragma unroll
    for (int r = 0; r < 4; ++r) rv[mi][r] = rinv[wrow * 64 + mi * 16 + quad * 4 + r];
  }
  for (int t = 0; t < 8; ++t) {
    int c0 = blockIdx.y * 1024 + t * 128 + wcol * 64;
    bf16x8 bf[4][4];
#pragma unroll
    for (int ni = 0; ni < 4; ++ni)
#pragma unroll
      for (int ks = 0; ks < 4; ++ks)
        bf[ni][ks] = *(const bf16x8*)(Bbf + (c0 + ni * 16 + m) * DIM + ks * 32 + quad * 8);
    f32x4 acc[4][4];
#pragma unroll
    for (int mi = 0; mi < 4; ++mi)
#pragma unroll
      for (int ni = 0; ni < 4; ++ni) acc[mi][ni] = (f32x4){0.f, 0.f, 0.f, 0.f};
#pragma unroll
    for (int ks = 0; ks < 4; ++ks)
#pragma unroll
      for (int mi = 0; mi < 4; ++mi)
#pragma unroll
        for (int ni = 0; ni < 4; ++ni)
          acc[mi][ni] = __builtin_amdgcn_mfma_f32_16x16x32_bf16(af[mi][ks], bf[ni][ks], acc[mi][ni], 0, 0, 0);
#pragma unroll
    for (int mi = 0; mi < 4; ++mi)
#pragma unroll
      for (int ni = 0; ni < 4; ++ni)
#pragma unroll
        for (int r = 0; r < 4; ++r) {
          float e = __expf(acc[mi][ni][r] * SCALE) * rv[mi][r];
          int row = blockIdx.x * 128 + wrow * 64 + mi * 16 + quad * 4 + r;
          P[row * NROW + c0 + ni * 16 + m] = f2bf(e);
        }
  }
}

// Per-label Gram: G[i,j] = SE_j * sum_k P_ik * (P_jk * ck_k); fused log-reduce.
// 128x128 tile, BK=64, LDS xor-swizzled chunks (2-way max on ds_read_b128).
__global__ __launch_bounds__(256, 2) void k_gram(const unsigned short* __restrict__ P,
                                                 const int* __restrict__ cnt,
                                                 const int* __restrict__ offs,
                                                 const int* __restrict__ sidx,
                                                 const float* __restrict__ SE,
                                                 const float* __restrict__ CK,
                                                 double* wa) {
  int lab = blockIdx.z;
  int c = cnt[lab], o = offs[lab];
  int i0 = blockIdx.y * 128, j0 = blockIdx.x * 128;
  if (i0 >= c || j0 >= c) return;
  __shared__ __align__(16) unsigned short Pt[128 * 64];
  __shared__ __align__(16) unsigned short Rt[128 * 64];
  __shared__ float rfj[128];
  __shared__ float red[4];
  int tid = threadIdx.x;
  if (tid < 128) {
    int jj = j0 + tid;
    rfj[tid] = (jj < c) ? SE[sidx[o + jj]] : 0.f;
  }
  __syncthreads();
  int wave = tid >> 6, lane = tid & 63;
  int wrow = wave >> 1, wcol = wave & 1;
  int m = lane & 15, quad = lane >> 4;
  // staging precompute: 4 rounds, slot = u*256+tid -> row=slot>>3, c8=slot&7
  const unsigned short* gpi[4];
  const unsigned short* gpj[4];
  int ldso[4], cko[4];
#pragma unroll
  for (int u = 0; u < 4; ++u) {
    int slot = u * 256 + tid, row = slot >> 3, c8 = slot & 7;
    int ri = o + i0 + row; if (ri > NROW - 1) ri = NROW - 1;
    int rj = o + j0 + row; if (rj > NROW - 1) rj = NROW - 1;
    gpi[u] = P + ri * NROW + c8 * 8;
    gpj[u] = P + rj * NROW + c8 * 8;
    ldso[u] = row * 64 + ((c8 ^ (row & 7)) * 8);
    cko[u] = c8 * 8;
  }
  f32x4 acc[4][4];
#pragma unroll
  for (int mi = 0; mi < 4; ++mi)
#pragma unroll
    for (int ni = 0; ni < 4; ++ni) acc[mi][ni] = (f32x4){0.f, 0.f, 0.f, 0.f};

  for (int k0 = 0; k0 < NROW; k0 += 64) {
    __syncthreads();
#pragma unroll
    for (int u = 0; u < 4; ++u) {
      bf16x8 pvv = *(const bf16x8*)(gpi[u] + k0);
      *(bf16x8*)(Pt + ldso[u]) = pvv;
      bf16x8 rvv = *(const bf16x8*)(gpj[u] + k0);
      f32x4 ck0 = *(const f32x4*)(CK + k0 + cko[u]);
      f32x4 ck1 = *(const f32x4*)(CK + k0 + cko[u] + 4);
      bf16x8 ro;
      ro[0] = (short)f2bf(bf2f(rvv[0]) * ck0[0]);
      ro[1] = (short)f2bf(bf2f(rvv[1]) * ck0[1]);
      ro[2] = (short)f2bf(bf2f(rvv[2]) * ck0[2]);
      ro[3] = (short)f2bf(bf2f(rvv[3]) * ck0[3]);
      ro[4] = (short)f2bf(bf2f(rvv[4]) * ck1[0]);
      ro[5] = (short)f2bf(bf2f(rvv[5]) * ck1[1]);
      ro[6] = (short)f2bf(bf2f(rvv[6]) * ck1[2]);
      ro[7] = (short)f2bf(bf2f(rvv[7]) * ck1[3]);
      *(bf16x8*)(Rt + ldso[u]) = ro;
    }
    __syncthreads();
#pragma unroll
    for (int ks = 0; ks < 2; ++ks) {
      bf16x8 pa[4], rb[4];
#pragma unroll
      for (int mi = 0; mi < 4; ++mi) {
        int row = wrow * 64 + mi * 16 + m;
        pa[mi] = *(const bf16x8*)(Pt + row * 64 + (((ks * 4 + quad) ^ (row & 7)) * 8));
      }
#pragma unroll
      for (int ni = 0; ni < 4; ++ni) {
        int row = wcol * 64 + ni * 16 + m;
        rb[ni] = *(const bf16x8*)(Rt + row * 64 + (((ks * 4 + quad) ^ (row & 7)) * 8));
      }
#pragma unroll
      for (int mi = 0; mi < 4; ++mi)
#pragma unroll
        for (int ni = 0; ni < 4; ++ni)
          acc[mi][ni] = __builtin_amdgcn_mfma_f32_16x16x32_bf16(pa[mi], rb[ni], acc[mi][ni], 0, 0, 0);
    }
  }
  float sej[4];
#pragma unroll
  for (int ni = 0; ni < 4; ++ni) sej[ni] = rfj[wcol * 64 + ni * 16 + m];
  float lsum = 0.f;
#pragma unroll
  for (int mi = 0; mi < 4; ++mi)
#pragma unroll
    for (int ni = 0; ni < 4; ++ni)
#pragma unroll
      for (int r = 0; r < 4; ++r) {
        int i = i0 + wrow * 64 + mi * 16 + quad * 4 + r;
        int j = j0 + wcol * 64 + ni * 16 + m;
        if (i < c && j < c) lsum += __logf(EPSf + sej[ni] * acc[mi][ni][r]);
      }
#pragma unroll
  for (int off = 32; off; off >>= 1) lsum += __shfl_down(lsum, off);
  if (lane == 0) red[wave] = lsum;
  __syncthreads();
  if (tid == 0) {
    double tot = (double)red[0] + (double)red[1] + (double)red[2] + (double)red[3];
    atomicAdd(wa, -tot / (8192.0 * (double)c));
  }
}

__global__ void k_finish(const double* wa, const double* va, float* out) {
  out[0] = (float)(*wa);
  out[1] = (float)(*va);
}

extern "C" void kernel_launch(void* const* d_in, const int* in_sizes, int n_in,
                              void* d_out, int out_size, void* d_ws, size_t ws_size,
                              hipStream_t stream) {
  const float* A = (const float*)d_in[0];
  const float* B = (const float*)d_in[1];
  const int* LAB = (const int*)d_in[2];
  float* out = (float*)d_out;
  char* w = (char*)d_ws;
  double* WA = (double*)(w + O_WA);
  double* VA = (double*)(w + O_VA);
  int* CNT = (int*)(w + O_CNT);
  int* OFFS = (int*)(w + O_OFF);
  int* SIDX = (int*)(w + O_SIDX);
  float* SEa = (float*)(w + O_SE);
  float* CV = (float*)(w + O_CV);
  float* CK = (float*)(w + O_CK);
  float* PS = (float*)(w + O_PS);
  float* PC = (float*)(w + O_PC);
  float* PV = (float*)(w + O_PV);
  unsigned short* ABF = (unsigned short*)(w + O_ABF);
  unsigned short* BBF = (unsigned short*)(w + O_BBF);
  unsigned short* P = (unsigned short*)(w + O_P);

  k_bucket<<<1, 256, 0, stream>>>(LAB, CNT, OFFS, SIDX, WA, VA);
  k_convert<<<512, 256, 0, stream>>>(A, ABF);
  k_convert<<<512, 256, 0, stream>>>(B, BBF);
  k_rowstats<<<dim3(64, 8), 256, 0, stream>>>(ABF, BBF, PS);
  k_merge_row<<<32, 256, 0, stream>>>(PS, SEa, CV);
  k_colstats<<<dim3(64, 8), 256, 0, stream>>>(BBF, ABF, CV, PC, PV);
  k_merge_col<<<32, 256, 0, stream>>>(PC, PV, CK, VA);
  k_fill<<<dim3(64, 8), 256, 0, stream>>>(ABF, BBF, SIDX, CV, P);
  k_gram<<<dim3(10, 10, 10), 256, 0, stream>>>(P, CNT, OFFS, SIDX, SEa, CK, WA);
  k_finish<<<1, 1, 0, stream>>>(WA, VA, out);
}

// Round 4
// 395.099 us; speedup vs baseline: 8.5256x; 1.1813x over previous
//
#include <hip/hip_runtime.h>

// WalkerVisitLosses, round 4 (round-3 design, __exp2f -> __builtin_amdgcn_exp2f).
// p_raw = a.b; scaled inputs A'=A*SF, B'=B*SF with SF^2 = log2(e)/sqrt(128),
// so E = exp(p/sqrt(128)) = exp2(A'.B'^T). No-max softmax (p ~ N(0,1), safe).
//   SE_i = sum_k E_ik  (sorted-row space),  CS_k = sum_i E_ik
//   Ehat[p,k] = E[p,k]*sqrt(1/CS_k)  -> S = Ehat.Ehat^T symmetric
//   aba[i,j] = S[i,j]/SE_i ; walker needs only same-label (i,j): per-label
//   upper-triangle 128x128 tile pairs, split-K=4, bf16 partial tiles, then
//   reduce pass does log(eps + S*ISE_i) (+ mirrored term for off-diag tiles).
//   visit_k = sum_p E[p,k]/SE_p via a memory-bound pass that also writes Ehat.

typedef __attribute__((ext_vector_type(8))) short bf16x8;
typedef __attribute__((ext_vector_type(4))) float f32x4;

#define NROW 8192
#define DIM 128
#define NLAB 10
#define EPSf 1e-8f
#define SF 0.35709582f /* sqrt( log2(e)/sqrt(128) ) */
#define SPLIT 4
#define NPAIR 36   /* supports up to 8 row-tiles per label */
#define SPSTRIDE (360 * 16384) /* elements per split: 10 labels * 36 pairs * 128*128 */

// workspace byte offsets (total ~186.3 MB)
#define O_WA 0
#define O_VA 8
#define O_CNT 64
#define O_OFF 128
#define O_SIDX 256
#define O_PS 33280
#define O_CS 557568
#define O_VK 590336
#define O_CV 623104
#define O_CKS 655872
#define O_ABF 688640
#define O_BBF 2785792
#define O_E 4882944
#define O_SP 139100672

__device__ __forceinline__ unsigned short f2bf(float f) {
  unsigned u = __builtin_bit_cast(unsigned, f);
  u += 0x7fffu + ((u >> 16) & 1u);
  return (unsigned short)(u >> 16);
}
__device__ __forceinline__ float bf2f(unsigned short s) {
  unsigned u = ((unsigned)s) << 16;
  return __builtin_bit_cast(float, u);
}

__global__ __launch_bounds__(256) void k_bucket(const int* __restrict__ lab,
                                                int* cnt, int* offs, int* sidx,
                                                double* wa, double* va,
                                                float* cs, float* vk) {
  __shared__ int lc[NLAB], lcur[NLAB];
  int tid = threadIdx.x;
  if (tid < NLAB) lc[tid] = 0;
  __syncthreads();
  for (int i = tid; i < NROW; i += 256) {
    int l = lab[i]; l = l < 0 ? 0 : (l > 9 ? 9 : l);
    atomicAdd(&lc[l], 1);
  }
  for (int i = tid; i < NROW; i += 256) { cs[i] = 0.f; vk[i] = 0.f; }
  __syncthreads();
  if (tid == 0) {
    int run = 0;
    for (int l = 0; l < NLAB; ++l) { cnt[l] = lc[l]; offs[l] = run; lcur[l] = run; run += lc[l]; }
    *wa = 0.0; *va = 0.0;
  }
  __syncthreads();
  for (int i = tid; i < NROW; i += 256) {
    int l = lab[i]; l = l < 0 ? 0 : (l > 9 ? 9 : l);
    int p = atomicAdd(&lcur[l], 1);
    sidx[p] = i;
  }
}

__global__ __launch_bounds__(256) void k_convert(const float* __restrict__ X,
                                                 unsigned short* __restrict__ Y) {
  int i = (blockIdx.x * 256 + threadIdx.x) * 8;
  f32x4 a = *(const f32x4*)(X + i);
  f32x4 b = *(const f32x4*)(X + i + 4);
  bf16x8 o;
  o[0] = (short)f2bf(a[0] * SF); o[1] = (short)f2bf(a[1] * SF);
  o[2] = (short)f2bf(a[2] * SF); o[3] = (short)f2bf(a[3] * SF);
  o[4] = (short)f2bf(b[0] * SF); o[5] = (short)f2bf(b[1] * SF);
  o[6] = (short)f2bf(b[2] * SF); o[7] = (short)f2bf(b[3] * SF);
  *(bf16x8*)(Y + i) = o;
}

// One pass: E[p,k]=exp2(A'_sidx[p] . B'_k) bf16 store + row partial sums (ps)
// + col sums (atomic CS). Block: 128 sorted rows x 1024 cols; 4 waves 2x2.
__global__ __launch_bounds__(256, 2) void k_score(const unsigned short* __restrict__ Abf,
                                                  const unsigned short* __restrict__ Bbf,
                                                  const int* __restrict__ sidx,
                                                  unsigned short* __restrict__ E,
                                                  float* __restrict__ ps,
                                                  float* __restrict__ CS) {
  __shared__ int gidx[128];
  int tid = threadIdx.x;
  if (tid < 128) gidx[tid] = sidx[blockIdx.x * 128 + tid];
  __syncthreads();
  int wave = tid >> 6, lane = tid & 63;
  int wrow = wave >> 1, wcol = wave & 1;
  int m = lane & 15, quad = lane >> 4;
  bf16x8 af[4][4];
#pragma unroll
  for (int mi = 0; mi < 4; ++mi) {
    int gi = gidx[wrow * 64 + mi * 16 + m];
#pragma unroll
    for (int ks = 0; ks < 4; ++ks)
      af[mi][ks] = *(const bf16x8*)(Abf + gi * DIM + ks * 32 + quad * 8);
  }
  float tsum[4][4];
#pragma unroll
  for (int mi = 0; mi < 4; ++mi)
#pragma unroll
    for (int r = 0; r < 4; ++r) tsum[mi][r] = 0.f;
  int p0 = blockIdx.x * 128 + wrow * 64;
  for (int t = 0; t < 8; ++t) {
    int c0 = blockIdx.y * 1024 + t * 128 + wcol * 64;
    bf16x8 bfr[4][4];
#pragma unroll
    for (int ni = 0; ni < 4; ++ni)
#pragma unroll
      for (int ks = 0; ks < 4; ++ks)
        bfr[ni][ks] = *(const bf16x8*)(Bbf + (c0 + ni * 16 + m) * DIM + ks * 32 + quad * 8);
    f32x4 acc[4][4];
#pragma unroll
    for (int mi = 0; mi < 4; ++mi)
#pragma unroll
      for (int ni = 0; ni < 4; ++ni) acc[mi][ni] = (f32x4){0.f, 0.f, 0.f, 0.f};
#pragma unroll
    for (int ks = 0; ks < 4; ++ks)
#pragma unroll
      for (int mi = 0; mi < 4; ++mi)
#pragma unroll
        for (int ni = 0; ni < 4; ++ni)
          acc[mi][ni] = __builtin_amdgcn_mfma_f32_16x16x32_bf16(af[mi][ks], bfr[ni][ks], acc[mi][ni], 0, 0, 0);
    float csum[4] = {0.f, 0.f, 0.f, 0.f};
#pragma unroll
    for (int mi = 0; mi < 4; ++mi)
#pragma unroll
      for (int ni = 0; ni < 4; ++ni)
#pragma unroll
        for (int r = 0; r < 4; ++r) {
          float e = __builtin_amdgcn_exp2f(acc[mi][ni][r]);
          int row = p0 + mi * 16 + quad * 4 + r;
          E[(size_t)row * NROW + c0 + ni * 16 + m] = f2bf(e);
          tsum[mi][r] += e;
          csum[ni] += e;
        }
#pragma unroll
    for (int ni = 0; ni < 4; ++ni) {
      csum[ni] += __shfl_xor(csum[ni], 16);
      csum[ni] += __shfl_xor(csum[ni], 32);
    }
    if (lane < 16) {
#pragma unroll
      for (int ni = 0; ni < 4; ++ni) atomicAdd(&CS[c0 + ni * 16 + lane], csum[ni]);
    }
  }
#pragma unroll
  for (int off = 1; off < 16; off <<= 1)
#pragma unroll
    for (int mi = 0; mi < 4; ++mi)
#pragma unroll
      for (int r = 0; r < 4; ++r) tsum[mi][r] += __shfl_xor(tsum[mi][r], off);
  if (m == 0) {
#pragma unroll
    for (int mi = 0; mi < 4; ++mi)
#pragma unroll
      for (int r = 0; r < 4; ++r)
        ps[(blockIdx.y * 2 + wcol) * NROW + p0 + mi * 16 + quad * 4 + r] = tsum[mi][r];
  }
}

__global__ __launch_bounds__(256) void k_mstats(const float* __restrict__ ps,
                                                const float* __restrict__ CS,
                                                float* __restrict__ CVs,
                                                float* __restrict__ CKS) {
  int i = blockIdx.x * 256 + threadIdx.x;
  float s = 0.f;
#pragma unroll
  for (int t = 0; t < 16; ++t) s += ps[t * NROW + i];
  CVs[i] = 1.f / s;
  CKS[i] = rsqrtf(CS[i]);
}

// Memory-bound pass: visit partial vk[k] += E[p,k]*CVs[p]; Ehat = E*CKS[k] in place.
__global__ __launch_bounds__(256) void k_visit_scale(unsigned short* __restrict__ E,
                                                     const float* __restrict__ CVs,
                                                     const float* __restrict__ CKS,
                                                     float* __restrict__ VK) {
  int c8 = blockIdx.x * 2048 + threadIdx.x * 8;
  int r0 = blockIdx.y * 128;
  float ck[8], va[8];
#pragma unroll
  for (int j = 0; j < 8; ++j) { ck[j] = CKS[c8 + j]; va[j] = 0.f; }
  for (int r = 0; r < 128; ++r) {
    size_t idx = (size_t)(r0 + r) * NROW + c8;
    bf16x8 e = *(const bf16x8*)(E + idx);
    float cv = CVs[r0 + r];
    bf16x8 o;
#pragma unroll
    for (int j = 0; j < 8; ++j) {
      float ev = bf2f((unsigned short)e[j]);
      va[j] = fmaf(ev, cv, va[j]);
      o[j] = (short)f2bf(ev * ck[j]);
    }
    *(bf16x8*)(E + idx) = o;
  }
#pragma unroll
  for (int j = 0; j < 8; ++j) atomicAdd(&VK[c8 + j], va[j]);
}

__global__ __launch_bounds__(256) void k_vloss(const float* __restrict__ VK, double* va) {
  __shared__ float red[4];
  int tid = threadIdx.x;
  int i = blockIdx.x * 256 + tid;
  float l = __logf(EPSf + VK[i] * (1.f / 8192.f));
#pragma unroll
  for (int off = 32; off; off >>= 1) l += __shfl_down(l, off);
  if ((tid & 63) == 0) red[tid >> 6] = l;
  __syncthreads();
  if (tid == 0) {
    double tot = (double)red[0] + (double)red[1] + (double)red[2] + (double)red[3];
    atomicAdd(va, -tot / 8192.0);
  }
}

// Per-label symmetric Gram, split-K. Tile pair (ti<=tj), 128x128, BK=64.
// Pure-copy LDS staging (xor-swizzled -> 2-way max on ds_read_b128).
__global__ __launch_bounds__(256, 2) void k_gram(const unsigned short* __restrict__ Eh,
                                                 const int* __restrict__ cnt,
                                                 const int* __restrict__ offs,
                                                 unsigned short* __restrict__ Spart) {
  int lab = blockIdx.z, split = blockIdx.y, pidx = blockIdx.x;
  int tj = 0;
  while ((tj + 1) * (tj + 2) / 2 <= pidx) ++tj;
  int ti = pidx - tj * (tj + 1) / 2;
  int c = cnt[lab], o = offs[lab];
  if (tj * 128 >= c) return;
  const bool diag = (ti == tj);
  __shared__ __align__(16) unsigned short Pt[128 * 64];
  __shared__ __align__(16) unsigned short Rt[128 * 64];
  int tid = threadIdx.x;
  int wave = tid >> 6, lane = tid & 63;
  int wrow = wave >> 1, wcol = wave & 1;
  int m = lane & 15, quad = lane >> 4;
  const unsigned short* pp[4];
  const unsigned short* pr[4];
  int lo[4];
#pragma unroll
  for (int v = 0; v < 4; ++v) {
    int slot = v * 256 + tid, row = slot >> 3, c8 = slot & 7;
    int ri = o + ti * 128 + row; if (ri > NROW - 1) ri = NROW - 1;
    int rj = o + tj * 128 + row; if (rj > NROW - 1) rj = NROW - 1;
    pp[v] = Eh + (size_t)ri * NROW + split * 2048 + c8 * 8;
    pr[v] = Eh + (size_t)rj * NROW + split * 2048 + c8 * 8;
    lo[v] = row * 64 + ((c8 ^ (row & 7)) * 8);
  }
  f32x4 acc[4][4];
#pragma unroll
  for (int mi = 0; mi < 4; ++mi)
#pragma unroll
    for (int ni = 0; ni < 4; ++ni) acc[mi][ni] = (f32x4){0.f, 0.f, 0.f, 0.f};
  const unsigned short* Bt = diag ? Pt : Rt;
  for (int t = 0; t < 32; ++t) {
    __syncthreads();
    bf16x8 dp[4], dr[4];
#pragma unroll
    for (int v = 0; v < 4; ++v) {
      dp[v] = *(const bf16x8*)(pp[v]); pp[v] += 64;
      if (!diag) { dr[v] = *(const bf16x8*)(pr[v]); pr[v] += 64; }
    }
#pragma unroll
    for (int v = 0; v < 4; ++v) {
      *(bf16x8*)(Pt + lo[v]) = dp[v];
      if (!diag) *(bf16x8*)(Rt + lo[v]) = dr[v];
    }
    __syncthreads();
#pragma unroll
    for (int ks = 0; ks < 2; ++ks) {
      bf16x8 pa[4], rb[4];
#pragma unroll
      for (int mi = 0; mi < 4; ++mi) {
        int row = wrow * 64 + mi * 16 + m;
        pa[mi] = *(const bf16x8*)(Pt + row * 64 + (((ks * 4 + quad) ^ (row & 7)) * 8));
      }
#pragma unroll
      for (int ni = 0; ni < 4; ++ni) {
        int row = wcol * 64 + ni * 16 + m;
        rb[ni] = *(const bf16x8*)(Bt + row * 64 + (((ks * 4 + quad) ^ (row & 7)) * 8));
      }
#pragma unroll
      for (int mi = 0; mi < 4; ++mi)
#pragma unroll
        for (int ni = 0; ni < 4; ++ni)
          acc[mi][ni] = __builtin_amdgcn_mfma_f32_16x16x32_bf16(pa[mi], rb[ni], acc[mi][ni], 0, 0, 0);
    }
  }
  size_t base = (size_t)(split * SPSTRIDE) + (size_t)(lab * NPAIR + pidx) * 16384;
#pragma unroll
  for (int mi = 0; mi < 4; ++mi)
#pragma unroll
    for (int ni = 0; ni < 4; ++ni)
#pragma unroll
      for (int r = 0; r < 4; ++r) {
        int cmp = (mi * 4 + ni) * 4 + r;
        Spart[base + cmp * 256 + tid] = f2bf(acc[mi][ni][r]);
      }
}

// Sum split partials, apply log(eps + S * ISE), accumulate walker loss.
__global__ __launch_bounds__(256) void k_reduce(const unsigned short* __restrict__ Spart,
                                                const int* __restrict__ cnt,
                                                const int* __restrict__ offs,
                                                const float* __restrict__ CVs,
                                                double* wa) {
  int lab = blockIdx.y, pidx = blockIdx.x;
  int tj = 0;
  while ((tj + 1) * (tj + 2) / 2 <= pidx) ++tj;
  int ti = pidx - tj * (tj + 1) / 2;
  int c = cnt[lab], o = offs[lab];
  if (tj * 128 >= c) return;
  __shared__ float isei[128], isej[128];
  __shared__ float red[4];
  int tid = threadIdx.x;
  if (tid < 128) {
    int ri = o + ti * 128 + tid; if (ri > NROW - 1) ri = NROW - 1;
    int rj = o + tj * 128 + tid; if (rj > NROW - 1) rj = NROW - 1;
    isei[tid] = CVs[ri];
    isej[tid] = CVs[rj];
  }
  __syncthreads();
  int wave = tid >> 6, lane = tid & 63;
  int wrow = wave >> 1, wcol = wave & 1;
  int m = lane & 15, quad = lane >> 4;
  size_t base = (size_t)(lab * NPAIR + pidx) * 16384;
  float lsum = 0.f;
#pragma unroll
  for (int mi = 0; mi < 4; ++mi)
#pragma unroll
    for (int ni = 0; ni < 4; ++ni)
#pragma unroll
      for (int r = 0; r < 4; ++r) {
        int cmp = (mi * 4 + ni) * 4 + r;
        size_t off = base + cmp * 256 + tid;
        float S = bf2f(Spart[off]) + bf2f(Spart[SPSTRIDE + off]) +
                  bf2f(Spart[2 * SPSTRIDE + off]) + bf2f(Spart[3 * SPSTRIDE + off]);
        int il = wrow * 64 + mi * 16 + quad * 4 + r;
        int jl = wcol * 64 + ni * 16 + m;
        int i = ti * 128 + il, j = tj * 128 + jl;
        if (i < c && j < c) {
          lsum += __logf(EPSf + S * isei[il]);
          if (ti != tj) lsum += __logf(EPSf + S * isej[jl]);
        }
      }
#pragma unroll
  for (int off2 = 32; off2; off2 >>= 1) lsum += __shfl_down(lsum, off2);
  if (lane == 0) red[wave] = lsum;
  __syncthreads();
  if (tid == 0) {
    double tot = (double)red[0] + (double)red[1] + (double)red[2] + (double)red[3];
    atomicAdd(wa, -tot / (8192.0 * (double)c));
  }
}

__global__ void k_finish(const double* wa, const double* va, float* out) {
  out[0] = (float)(*wa);
  out[1] = (float)(*va);
}

extern "C" void kernel_launch(void* const* d_in, const int* in_sizes, int n_in,
                              void* d_out, int out_size, void* d_ws, size_t ws_size,
                              hipStream_t stream) {
  const float* A = (const float*)d_in[0];
  const float* B = (const float*)d_in[1];
  const int* LAB = (const int*)d_in[2];
  float* out = (float*)d_out;
  char* w = (char*)d_ws;
  double* WA = (double*)(w + O_WA);
  double* VA = (double*)(w + O_VA);
  int* CNT = (int*)(w + O_CNT);
  int* OFFS = (int*)(w + O_OFF);
  int* SIDX = (int*)(w + O_SIDX);
  float* PS = (float*)(w + O_PS);
  float* CS = (float*)(w + O_CS);
  float* VK = (float*)(w + O_VK);
  float* CVs = (float*)(w + O_CV);
  float* CKS = (float*)(w + O_CKS);
  unsigned short* ABF = (unsigned short*)(w + O_ABF);
  unsigned short* BBF = (unsigned short*)(w + O_BBF);
  unsigned short* E = (unsigned short*)(w + O_E);
  unsigned short* SP = (unsigned short*)(w + O_SP);

  k_bucket<<<1, 256, 0, stream>>>(LAB, CNT, OFFS, SIDX, WA, VA, CS, VK);
  k_convert<<<512, 256, 0, stream>>>(A, ABF);
  k_convert<<<512, 256, 0, stream>>>(B, BBF);
  k_score<<<dim3(64, 8), 256, 0, stream>>>(ABF, BBF, SIDX, E, PS, CS);
  k_mstats<<<32, 256, 0, stream>>>(PS, CS, CVs, CKS);
  k_visit_scale<<<dim3(4, 64), 256, 0, stream>>>(E, CVs, CKS, VK);
  k_vloss<<<32, 256, 0, stream>>>(VK, VA);
  k_gram<<<dim3(NPAIR, SPLIT, NLAB), 256, 0, stream>>>(E, CNT, OFFS, SP);
  k_reduce<<<dim3(NPAIR, NLAB), 256, 0, stream>>>(SP, CNT, OFFS, CVs, WA);
  k_finish<<<1, 1, 0, stream>>>(WA, VA, out);
}

// Round 5
// 352.653 us; speedup vs baseline: 9.5518x; 1.1204x over previous
//
#include <hip/hip_runtime.h>

// WalkerVisitLosses, round 5.
// Same math as round 4:
//   E = exp2(A'.B'^T), SE_i row sums, CS_k col sums, Ehat = E*rsqrt(CS),
//   S = Ehat.Ehat^T symmetric, walker = mean_i sum_{j same label}
//       -log(eps + S_ij/SE_i)/cnt ; visit from E/SE col means.
// Round-5 deltas: k_gram occupancy 2->4 blocks/CU, XCD-locality grid remap
// (gid&7 = XCD, each XCD owns 5 (lab,split) groups whose 3.35MB E-slice fits
// its 4MB L2), ushort4-packed Spart stores, wider k_visit_scale grid.

typedef __attribute__((ext_vector_type(8))) short bf16x8;
typedef __attribute__((ext_vector_type(4))) float f32x4;

#define NROW 8192
#define DIM 128
#define NLAB 10
#define EPSf 1e-8f
#define SF 0.35709582f /* sqrt( log2(e)/sqrt(128) ) */
#define SPLIT 4
#define NPAIR 36   /* supports up to 8 row-tiles per label */
#define SPSTRIDE (360 * 16384) /* elements per split: 10 labels * 36 pairs * 128*128 */

// workspace byte offsets (total ~186.3 MB)
#define O_WA 0
#define O_VA 8
#define O_CNT 64
#define O_OFF 128
#define O_SIDX 256
#define O_PS 33280
#define O_CS 557568
#define O_VK 590336
#define O_CV 623104
#define O_CKS 655872
#define O_ABF 688640
#define O_BBF 2785792
#define O_E 4882944
#define O_SP 139100672

__device__ __forceinline__ unsigned short f2bf(float f) {
  unsigned u = __builtin_bit_cast(unsigned, f);
  u += 0x7fffu + ((u >> 16) & 1u);
  return (unsigned short)(u >> 16);
}
__device__ __forceinline__ float bf2f(unsigned short s) {
  unsigned u = ((unsigned)s) << 16;
  return __builtin_bit_cast(float, u);
}

__global__ __launch_bounds__(256) void k_bucket(const int* __restrict__ lab,
                                                int* cnt, int* offs, int* sidx,
                                                double* wa, double* va,
                                                float* cs, float* vk) {
  __shared__ int lc[NLAB], lcur[NLAB];
  int tid = threadIdx.x;
  if (tid < NLAB) lc[tid] = 0;
  __syncthreads();
  for (int i = tid; i < NROW; i += 256) {
    int l = lab[i]; l = l < 0 ? 0 : (l > 9 ? 9 : l);
    atomicAdd(&lc[l], 1);
  }
  for (int i = tid; i < NROW; i += 256) { cs[i] = 0.f; vk[i] = 0.f; }
  __syncthreads();
  if (tid == 0) {
    int run = 0;
    for (int l = 0; l < NLAB; ++l) { cnt[l] = lc[l]; offs[l] = run; lcur[l] = run; run += lc[l]; }
    *wa = 0.0; *va = 0.0;
  }
  __syncthreads();
  for (int i = tid; i < NROW; i += 256) {
    int l = lab[i]; l = l < 0 ? 0 : (l > 9 ? 9 : l);
    int p = atomicAdd(&lcur[l], 1);
    sidx[p] = i;
  }
}

__global__ __launch_bounds__(256) void k_convert(const float* __restrict__ X,
                                                 unsigned short* __restrict__ Y) {
  int i = (blockIdx.x * 256 + threadIdx.x) * 8;
  f32x4 a = *(const f32x4*)(X + i);
  f32x4 b = *(const f32x4*)(X + i + 4);
  bf16x8 o;
  o[0] = (short)f2bf(a[0] * SF); o[1] = (short)f2bf(a[1] * SF);
  o[2] = (short)f2bf(a[2] * SF); o[3] = (short)f2bf(a[3] * SF);
  o[4] = (short)f2bf(b[0] * SF); o[5] = (short)f2bf(b[1] * SF);
  o[6] = (short)f2bf(b[2] * SF); o[7] = (short)f2bf(b[3] * SF);
  *(bf16x8*)(Y + i) = o;
}

// One pass: E[p,k]=exp2(A'_sidx[p] . B'_k) bf16 store + row partial sums (ps)
// + col sums (atomic CS). Block: 128 sorted rows x 1024 cols; 4 waves 2x2.
__global__ __launch_bounds__(256, 2) void k_score(const unsigned short* __restrict__ Abf,
                                                  const unsigned short* __restrict__ Bbf,
                                                  const int* __restrict__ sidx,
                                                  unsigned short* __restrict__ E,
                                                  float* __restrict__ ps,
                                                  float* __restrict__ CS) {
  __shared__ int gidx[128];
  int tid = threadIdx.x;
  if (tid < 128) gidx[tid] = sidx[blockIdx.x * 128 + tid];
  __syncthreads();
  int wave = tid >> 6, lane = tid & 63;
  int wrow = wave >> 1, wcol = wave & 1;
  int m = lane & 15, quad = lane >> 4;
  bf16x8 af[4][4];
#pragma unroll
  for (int mi = 0; mi < 4; ++mi) {
    int gi = gidx[wrow * 64 + mi * 16 + m];
#pragma unroll
    for (int ks = 0; ks < 4; ++ks)
      af[mi][ks] = *(const bf16x8*)(Abf + gi * DIM + ks * 32 + quad * 8);
  }
  float tsum[4][4];
#pragma unroll
  for (int mi = 0; mi < 4; ++mi)
#pragma unroll
    for (int r = 0; r < 4; ++r) tsum[mi][r] = 0.f;
  int p0 = blockIdx.x * 128 + wrow * 64;
  for (int t = 0; t < 8; ++t) {
    int c0 = blockIdx.y * 1024 + t * 128 + wcol * 64;
    bf16x8 bfr[4][4];
#pragma unroll
    for (int ni = 0; ni < 4; ++ni)
#pragma unroll
      for (int ks = 0; ks < 4; ++ks)
        bfr[ni][ks] = *(const bf16x8*)(Bbf + (c0 + ni * 16 + m) * DIM + ks * 32 + quad * 8);
    f32x4 acc[4][4];
#pragma unroll
    for (int mi = 0; mi < 4; ++mi)
#pragma unroll
      for (int ni = 0; ni < 4; ++ni) acc[mi][ni] = (f32x4){0.f, 0.f, 0.f, 0.f};
#pragma unroll
    for (int ks = 0; ks < 4; ++ks)
#pragma unroll
      for (int mi = 0; mi < 4; ++mi)
#pragma unroll
        for (int ni = 0; ni < 4; ++ni)
          acc[mi][ni] = __builtin_amdgcn_mfma_f32_16x16x32_bf16(af[mi][ks], bfr[ni][ks], acc[mi][ni], 0, 0, 0);
    float csum[4] = {0.f, 0.f, 0.f, 0.f};
#pragma unroll
    for (int mi = 0; mi < 4; ++mi)
#pragma unroll
      for (int ni = 0; ni < 4; ++ni)
#pragma unroll
        for (int r = 0; r < 4; ++r) {
          float e = __builtin_amdgcn_exp2f(acc[mi][ni][r]);
          int row = p0 + mi * 16 + quad * 4 + r;
          E[(size_t)row * NROW + c0 + ni * 16 + m] = f2bf(e);
          tsum[mi][r] += e;
          csum[ni] += e;
        }
#pragma unroll
    for (int ni = 0; ni < 4; ++ni) {
      csum[ni] += __shfl_xor(csum[ni], 16);
      csum[ni] += __shfl_xor(csum[ni], 32);
    }
    if (lane < 16) {
#pragma unroll
      for (int ni = 0; ni < 4; ++ni) atomicAdd(&CS[c0 + ni * 16 + lane], csum[ni]);
    }
  }
#pragma unroll
  for (int off = 1; off < 16; off <<= 1)
#pragma unroll
    for (int mi = 0; mi < 4; ++mi)
#pragma unroll
      for (int r = 0; r < 4; ++r) tsum[mi][r] += __shfl_xor(tsum[mi][r], off);
  if (m == 0) {
#pragma unroll
    for (int mi = 0; mi < 4; ++mi)
#pragma unroll
      for (int r = 0; r < 4; ++r)
        ps[(blockIdx.y * 2 + wcol) * NROW + p0 + mi * 16 + quad * 4 + r] = tsum[mi][r];
  }
}

__global__ __launch_bounds__(256) void k_mstats(const float* __restrict__ ps,
                                                const float* __restrict__ CS,
                                                float* __restrict__ CVs,
                                                float* __restrict__ CKS) {
  int i = blockIdx.x * 256 + threadIdx.x;
  float s = 0.f;
#pragma unroll
  for (int t = 0; t < 16; ++t) s += ps[t * NROW + i];
  CVs[i] = 1.f / s;
  CKS[i] = rsqrtf(CS[i]);
}

// Memory-bound pass: visit partial vk[k] += E[p,k]*CVs[p]; Ehat = E*CKS[k] in place.
__global__ __launch_bounds__(256) void k_visit_scale(unsigned short* __restrict__ E,
                                                     const float* __restrict__ CVs,
                                                     const float* __restrict__ CKS,
                                                     float* __restrict__ VK) {
  int c8 = blockIdx.x * 2048 + threadIdx.x * 8;
  int r0 = blockIdx.y * 32;
  float ck[8], va[8];
#pragma unroll
  for (int j = 0; j < 8; ++j) { ck[j] = CKS[c8 + j]; va[j] = 0.f; }
  for (int r = 0; r < 32; ++r) {
    size_t idx = (size_t)(r0 + r) * NROW + c8;
    bf16x8 e = *(const bf16x8*)(E + idx);
    float cv = CVs[r0 + r];
    bf16x8 o;
#pragma unroll
    for (int j = 0; j < 8; ++j) {
      float ev = bf2f((unsigned short)e[j]);
      va[j] = fmaf(ev, cv, va[j]);
      o[j] = (short)f2bf(ev * ck[j]);
    }
    *(bf16x8*)(E + idx) = o;
  }
#pragma unroll
  for (int j = 0; j < 8; ++j) atomicAdd(&VK[c8 + j], va[j]);
}

__global__ __launch_bounds__(256) void k_vloss(const float* __restrict__ VK, double* va) {
  __shared__ float red[4];
  int tid = threadIdx.x;
  int i = blockIdx.x * 256 + tid;
  float l = __logf(EPSf + VK[i] * (1.f / 8192.f));
#pragma unroll
  for (int off = 32; off; off >>= 1) l += __shfl_down(l, off);
  if ((tid & 63) == 0) red[tid >> 6] = l;
  __syncthreads();
  if (tid == 0) {
    double tot = (double)red[0] + (double)red[1] + (double)red[2] + (double)red[3];
    atomicAdd(va, -tot / 8192.0);
  }
}

// Per-label symmetric Gram, split-K. Tile pair (ti<=tj), 128x128, BK=64.
// Pure-copy LDS staging (xor-swizzled -> 2-way max on ds_read_b128).
// 1D grid, XCD-locality decode: gid&7 = XCD (round-robin dispatch heuristic),
// each XCD owns 5 consecutive (lab,split) groups; a group's E-slice (~3.35MB)
// fits the XCD's 4MB L2, so pairs within the group reuse it.
__global__ __launch_bounds__(256, 4) void k_gram(const unsigned short* __restrict__ Eh,
                                                 const int* __restrict__ cnt,
                                                 const int* __restrict__ offs,
                                                 unsigned short* __restrict__ Spart) {
  int gid = blockIdx.x;             // 0..1439
  int xcd = gid & 7, slot = gid >> 3;  // slot 0..179
  int group = xcd * 5 + slot / NPAIR;  // 0..39
  int pidx = slot % NPAIR;
  int lab = group / SPLIT, split = group % SPLIT;
  int tj = 0;
  while ((tj + 1) * (tj + 2) / 2 <= pidx) ++tj;
  int ti = pidx - tj * (tj + 1) / 2;
  int c = cnt[lab], o = offs[lab];
  if (tj * 128 >= c) return;
  const bool diag = (ti == tj);
  __shared__ __align__(16) unsigned short Pt[128 * 64];
  __shared__ __align__(16) unsigned short Rt[128 * 64];
  int tid = threadIdx.x;
  int wave = tid >> 6, lane = tid & 63;
  int wrow = wave >> 1, wcol = wave & 1;
  int m = lane & 15, quad = lane >> 4;
  const unsigned short* pp[4];
  const unsigned short* pr[4];
  int lo[4];
#pragma unroll
  for (int v = 0; v < 4; ++v) {
    int slotv = v * 256 + tid, row = slotv >> 3, c8 = slotv & 7;
    int ri = o + ti * 128 + row; if (ri > NROW - 1) ri = NROW - 1;
    int rj = o + tj * 128 + row; if (rj > NROW - 1) rj = NROW - 1;
    pp[v] = Eh + (size_t)ri * NROW + split * 2048 + c8 * 8;
    pr[v] = Eh + (size_t)rj * NROW + split * 2048 + c8 * 8;
    lo[v] = row * 64 + ((c8 ^ (row & 7)) * 8);
  }
  f32x4 acc[4][4];
#pragma unroll
  for (int mi = 0; mi < 4; ++mi)
#pragma unroll
    for (int ni = 0; ni < 4; ++ni) acc[mi][ni] = (f32x4){0.f, 0.f, 0.f, 0.f};
  const unsigned short* Bt = diag ? Pt : Rt;
  for (int t = 0; t < 32; ++t) {
    __syncthreads();
    bf16x8 dp[4], dr[4];
#pragma unroll
    for (int v = 0; v < 4; ++v) {
      dp[v] = *(const bf16x8*)(pp[v]); pp[v] += 64;
      if (!diag) { dr[v] = *(const bf16x8*)(pr[v]); pr[v] += 64; }
    }
#pragma unroll
    for (int v = 0; v < 4; ++v) {
      *(bf16x8*)(Pt + lo[v]) = dp[v];
      if (!diag) *(bf16x8*)(Rt + lo[v]) = dr[v];
    }
    __syncthreads();
#pragma unroll
    for (int ks = 0; ks < 2; ++ks) {
      bf16x8 pa[4], rb[4];
#pragma unroll
      for (int mi = 0; mi < 4; ++mi) {
        int row = wrow * 64 + mi * 16 + m;
        pa[mi] = *(const bf16x8*)(Pt + row * 64 + (((ks * 4 + quad) ^ (row & 7)) * 8));
      }
#pragma unroll
      for (int ni = 0; ni < 4; ++ni) {
        int row = wcol * 64 + ni * 16 + m;
        rb[ni] = *(const bf16x8*)(Bt + row * 64 + (((ks * 4 + quad) ^ (row & 7)) * 8));
      }
#pragma unroll
      for (int mi = 0; mi < 4; ++mi)
#pragma unroll
        for (int ni = 0; ni < 4; ++ni)
          acc[mi][ni] = __builtin_amdgcn_mfma_f32_16x16x32_bf16(pa[mi], rb[ni], acc[mi][ni], 0, 0, 0);
    }
  }
  // layout: base + (mi*4+ni)*1024 + tid*4 + r  (ushort4-packed stores)
  size_t base = (size_t)(split * SPSTRIDE) + (size_t)(lab * NPAIR + pidx) * 16384;
#pragma unroll
  for (int mi = 0; mi < 4; ++mi)
#pragma unroll
    for (int ni = 0; ni < 4; ++ni) {
      ushort4 w4;
      w4.x = f2bf(acc[mi][ni][0]);
      w4.y = f2bf(acc[mi][ni][1]);
      w4.z = f2bf(acc[mi][ni][2]);
      w4.w = f2bf(acc[mi][ni][3]);
      *(ushort4*)(Spart + base + (size_t)(mi * 4 + ni) * 1024 + tid * 4) = w4;
    }
}

// Sum split partials, apply log(eps + S * ISE), accumulate walker loss.
__global__ __launch_bounds__(256) void k_reduce(const unsigned short* __restrict__ Spart,
                                                const int* __restrict__ cnt,
                                                const int* __restrict__ offs,
                                                const float* __restrict__ CVs,
                                                double* wa) {
  int lab = blockIdx.y, pidx = blockIdx.x;
  int tj = 0;
  while ((tj + 1) * (tj + 2) / 2 <= pidx) ++tj;
  int ti = pidx - tj * (tj + 1) / 2;
  int c = cnt[lab], o = offs[lab];
  if (tj * 128 >= c) return;
  __shared__ float isei[128], isej[128];
  __shared__ float red[4];
  int tid = threadIdx.x;
  if (tid < 128) {
    int ri = o + ti * 128 + tid; if (ri > NROW - 1) ri = NROW - 1;
    int rj = o + tj * 128 + tid; if (rj > NROW - 1) rj = NROW - 1;
    isei[tid] = CVs[ri];
    isej[tid] = CVs[rj];
  }
  __syncthreads();
  int wave = tid >> 6, lane = tid & 63;
  int wrow = wave >> 1, wcol = wave & 1;
  int m = lane & 15, quad = lane >> 4;
  size_t base = (size_t)(lab * NPAIR + pidx) * 16384;
  float lsum = 0.f;
#pragma unroll
  for (int mi = 0; mi < 4; ++mi)
#pragma unroll
    for (int ni = 0; ni < 4; ++ni) {
      size_t off = base + (size_t)(mi * 4 + ni) * 1024 + tid * 4;
      ushort4 s0 = *(const ushort4*)(Spart + off);
      ushort4 s1 = *(const ushort4*)(Spart + SPSTRIDE + off);
      ushort4 s2 = *(const ushort4*)(Spart + 2 * (size_t)SPSTRIDE + off);
      ushort4 s3 = *(const ushort4*)(Spart + 3 * (size_t)SPSTRIDE + off);
      float S[4];
      S[0] = bf2f(s0.x) + bf2f(s1.x) + bf2f(s2.x) + bf2f(s3.x);
      S[1] = bf2f(s0.y) + bf2f(s1.y) + bf2f(s2.y) + bf2f(s3.y);
      S[2] = bf2f(s0.z) + bf2f(s1.z) + bf2f(s2.z) + bf2f(s3.z);
      S[3] = bf2f(s0.w) + bf2f(s1.w) + bf2f(s2.w) + bf2f(s3.w);
      int jl = wcol * 64 + ni * 16 + m;
      int j = tj * 128 + jl;
#pragma unroll
      for (int r = 0; r < 4; ++r) {
        int il = wrow * 64 + mi * 16 + quad * 4 + r;
        int i = ti * 128 + il;
        if (i < c && j < c) {
          lsum += __logf(EPSf + S[r] * isei[il]);
          if (ti != tj) lsum += __logf(EPSf + S[r] * isej[jl]);
        }
      }
    }
#pragma unroll
  for (int off2 = 32; off2; off2 >>= 1) lsum += __shfl_down(lsum, off2);
  if (lane == 0) red[wave] = lsum;
  __syncthreads();
  if (tid == 0) {
    double tot = (double)red[0] + (double)red[1] + (double)red[2] + (double)red[3];
    atomicAdd(wa, -tot / (8192.0 * (double)c));
  }
}

__global__ void k_finish(const double* wa, const double* va, float* out) {
  out[0] = (float)(*wa);
  out[1] = (float)(*va);
}

extern "C" void kernel_launch(void* const* d_in, const int* in_sizes, int n_in,
                              void* d_out, int out_size, void* d_ws, size_t ws_size,
                              hipStream_t stream) {
  const float* A = (const float*)d_in[0];
  const float* B = (const float*)d_in[1];
  const int* LAB = (const int*)d_in[2];
  float* out = (float*)d_out;
  char* w = (char*)d_ws;
  double* WA = (double*)(w + O_WA);
  double* VA = (double*)(w + O_VA);
  int* CNT = (int*)(w + O_CNT);
  int* OFFS = (int*)(w + O_OFF);
  int* SIDX = (int*)(w + O_SIDX);
  float* PS = (float*)(w + O_PS);
  float* CS = (float*)(w + O_CS);
  float* VK = (float*)(w + O_VK);
  float* CVs = (float*)(w + O_CV);
  float* CKS = (float*)(w + O_CKS);
  unsigned short* ABF = (unsigned short*)(w + O_ABF);
  unsigned short* BBF = (unsigned short*)(w + O_BBF);
  unsigned short* E = (unsigned short*)(w + O_E);
  unsigned short* SP = (unsigned short*)(w + O_SP);

  k_bucket<<<1, 256, 0, stream>>>(LAB, CNT, OFFS, SIDX, WA, VA, CS, VK);
  k_convert<<<512, 256, 0, stream>>>(A, ABF);
  k_convert<<<512, 256, 0, stream>>>(B, BBF);
  k_score<<<dim3(64, 8), 256, 0, stream>>>(ABF, BBF, SIDX, E, PS, CS);
  k_mstats<<<32, 256, 0, stream>>>(PS, CS, CVs, CKS);
  k_visit_scale<<<dim3(4, 256), 256, 0, stream>>>(E, CVs, CKS, VK);
  k_vloss<<<32, 256, 0, stream>>>(VK, VA);
  k_gram<<<NPAIR * SPLIT * NLAB, 256, 0, stream>>>(E, CNT, OFFS, SP);
  k_reduce<<<dim3(NPAIR, NLAB), 256, 0, stream>>>(SP, CNT, OFFS, CVs, WA);
  k_finish<<<1, 1, 0, stream>>>(WA, VA, out);
}

// Round 6
// 304.019 us; speedup vs baseline: 11.0798x; 1.1600x over previous
//
#include <hip/hip_runtime.h>

// WalkerVisitLosses, round 6.
// E = exp2(A'.B'^T) (A'=A*SF, SF^2=log2(e)/sqrt(128)); SE_i row sums,
// CS_k col sums, ck_k=1/CS_k. S_ij = sum_k E_ik*ck_k*E_jk (symmetric),
// walker from log(eps + S*1/SE) on same-label tile pairs; visit = E^T.(1/SE)/N.
// Round-6 deltas: k_visit_scale ELIMINATED. E stays raw; k_gram folds ck into
// Rt staging (f32 mul + v_perm trunc-pack); visit is a read-only batched
// matvec with per-block partials (no in-place rewrite, no atomic storm).

typedef __attribute__((ext_vector_type(8))) short bf16x8;
typedef __attribute__((ext_vector_type(4))) float f32x4;

#define NROW 8192
#define DIM 128
#define NLAB 10
#define EPSf 1e-8f
#define SF 0.35709582f /* sqrt( log2(e)/sqrt(128) ) */
#define SPLIT 4
#define NPAIR 36   /* supports up to 8 row-tiles per label */
#define SPSTRIDE (360 * 16384) /* elements per split */

// workspace byte offsets (total ~190.3 MB)
#define O_WA 0
#define O_VA 8
#define O_CNT 64
#define O_OFF 128
#define O_SIDX 256
#define O_PS 33280
#define O_CS 557568
#define O_CV 623104
#define O_CKS 655872
#define O_ABF 688640
#define O_BBF 2785792
#define O_E 4882944
#define O_SP 139100672
#define O_PV 186286592

__device__ __forceinline__ unsigned short f2bf(float f) {
  unsigned u = __builtin_bit_cast(unsigned, f);
  u += 0x7fffu + ((u >> 16) & 1u);
  return (unsigned short)(u >> 16);
}
__device__ __forceinline__ float bf2f(unsigned short s) {
  unsigned u = ((unsigned)s) << 16;
  return __builtin_bit_cast(float, u);
}
// pack two f32 -> two bf16 (round-half-up) in one uint via v_perm
__device__ __forceinline__ unsigned pack2bf(float e0, float e1) {
  unsigned u0 = __builtin_bit_cast(unsigned, e0) + 0x8000u;
  unsigned u1 = __builtin_bit_cast(unsigned, e1) + 0x8000u;
  return __builtin_amdgcn_perm(u1, u0, 0x07060302u);
}

__global__ __launch_bounds__(256) void k_bucket(const int* __restrict__ lab,
                                                int* cnt, int* offs, int* sidx,
                                                double* wa, double* va,
                                                float* cs) {
  __shared__ int lc[NLAB], lcur[NLAB];
  int tid = threadIdx.x;
  if (tid < NLAB) lc[tid] = 0;
  __syncthreads();
  for (int i = tid; i < NROW; i += 256) {
    int l = lab[i]; l = l < 0 ? 0 : (l > 9 ? 9 : l);
    atomicAdd(&lc[l], 1);
  }
  for (int i = tid; i < NROW; i += 256) cs[i] = 0.f;
  __syncthreads();
  if (tid == 0) {
    int run = 0;
    for (int l = 0; l < NLAB; ++l) { cnt[l] = lc[l]; offs[l] = run; lcur[l] = run; run += lc[l]; }
    *wa = 0.0; *va = 0.0;
  }
  __syncthreads();
  for (int i = tid; i < NROW; i += 256) {
    int l = lab[i]; l = l < 0 ? 0 : (l > 9 ? 9 : l);
    int p = atomicAdd(&lcur[l], 1);
    sidx[p] = i;
  }
}

__global__ __launch_bounds__(256) void k_convert(const float* __restrict__ X,
                                                 unsigned short* __restrict__ Y) {
  int i = (blockIdx.x * 256 + threadIdx.x) * 8;
  f32x4 a = *(const f32x4*)(X + i);
  f32x4 b = *(const f32x4*)(X + i + 4);
  bf16x8 o;
  o[0] = (short)f2bf(a[0] * SF); o[1] = (short)f2bf(a[1] * SF);
  o[2] = (short)f2bf(a[2] * SF); o[3] = (short)f2bf(a[3] * SF);
  o[4] = (short)f2bf(b[0] * SF); o[5] = (short)f2bf(b[1] * SF);
  o[6] = (short)f2bf(b[2] * SF); o[7] = (short)f2bf(b[3] * SF);
  *(bf16x8*)(Y + i) = o;
}

// E[p,k]=exp2(A'_sidx[p].B'_k) bf16 store + row partial sums + col sums (atomic).
__global__ __launch_bounds__(256, 2) void k_score(const unsigned short* __restrict__ Abf,
                                                  const unsigned short* __restrict__ Bbf,
                                                  const int* __restrict__ sidx,
                                                  unsigned short* __restrict__ E,
                                                  float* __restrict__ ps,
                                                  float* __restrict__ CS) {
  __shared__ int gidx[128];
  int tid = threadIdx.x;
  if (tid < 128) gidx[tid] = sidx[blockIdx.x * 128 + tid];
  __syncthreads();
  int wave = tid >> 6, lane = tid & 63;
  int wrow = wave >> 1, wcol = wave & 1;
  int m = lane & 15, quad = lane >> 4;
  bf16x8 af[4][4];
#pragma unroll
  for (int mi = 0; mi < 4; ++mi) {
    int gi = gidx[wrow * 64 + mi * 16 + m];
#pragma unroll
    for (int ks = 0; ks < 4; ++ks)
      af[mi][ks] = *(const bf16x8*)(Abf + gi * DIM + ks * 32 + quad * 8);
  }
  float tsum[4][4];
#pragma unroll
  for (int mi = 0; mi < 4; ++mi)
#pragma unroll
    for (int r = 0; r < 4; ++r) tsum[mi][r] = 0.f;
  int p0 = blockIdx.x * 128 + wrow * 64;
  for (int t = 0; t < 8; ++t) {
    int c0 = blockIdx.y * 1024 + t * 128 + wcol * 64;
    bf16x8 bfr[4][4];
#pragma unroll
    for (int ni = 0; ni < 4; ++ni)
#pragma unroll
      for (int ks = 0; ks < 4; ++ks)
        bfr[ni][ks] = *(const bf16x8*)(Bbf + (c0 + ni * 16 + m) * DIM + ks * 32 + quad * 8);
    f32x4 acc[4][4];
#pragma unroll
    for (int mi = 0; mi < 4; ++mi)
#pragma unroll
      for (int ni = 0; ni < 4; ++ni) acc[mi][ni] = (f32x4){0.f, 0.f, 0.f, 0.f};
#pragma unroll
    for (int ks = 0; ks < 4; ++ks)
#pragma unroll
      for (int mi = 0; mi < 4; ++mi)
#pragma unroll
        for (int ni = 0; ni < 4; ++ni)
          acc[mi][ni] = __builtin_amdgcn_mfma_f32_16x16x32_bf16(af[mi][ks], bfr[ni][ks], acc[mi][ni], 0, 0, 0);
    float csum[4] = {0.f, 0.f, 0.f, 0.f};
#pragma unroll
    for (int mi = 0; mi < 4; ++mi)
#pragma unroll
      for (int ni = 0; ni < 4; ++ni)
#pragma unroll
        for (int r = 0; r < 4; ++r) {
          float e = __builtin_amdgcn_exp2f(acc[mi][ni][r]);
          int row = p0 + mi * 16 + quad * 4 + r;
          E[(size_t)row * NROW + c0 + ni * 16 + m] = f2bf(e);
          tsum[mi][r] += e;
          csum[ni] += e;
        }
#pragma unroll
    for (int ni = 0; ni < 4; ++ni) {
      csum[ni] += __shfl_xor(csum[ni], 16);
      csum[ni] += __shfl_xor(csum[ni], 32);
    }
    if (lane < 16) {
#pragma unroll
      for (int ni = 0; ni < 4; ++ni) atomicAdd(&CS[c0 + ni * 16 + lane], csum[ni]);
    }
  }
#pragma unroll
  for (int off = 1; off < 16; off <<= 1)
#pragma unroll
    for (int mi = 0; mi < 4; ++mi)
#pragma unroll
      for (int r = 0; r < 4; ++r) tsum[mi][r] += __shfl_xor(tsum[mi][r], off);
  if (m == 0) {
#pragma unroll
    for (int mi = 0; mi < 4; ++mi)
#pragma unroll
      for (int r = 0; r < 4; ++r)
        ps[(blockIdx.y * 2 + wcol) * NROW + p0 + mi * 16 + quad * 4 + r] = tsum[mi][r];
  }
}

__global__ __launch_bounds__(256) void k_mstats(const float* __restrict__ ps,
                                                const float* __restrict__ CS,
                                                float* __restrict__ CVs,
                                                float* __restrict__ CKS) {
  int i = blockIdx.x * 256 + threadIdx.x;
  float s = 0.f;
#pragma unroll
  for (int t = 0; t < 16; ++t) s += ps[t * NROW + i];
  CVs[i] = 1.f / s;
  CKS[i] = 1.f / CS[i];
}

// Read-only matvec: PV[rowgroup, k] = sum_{r in group} E[r,k]*CV[r].
// 4-row load batching for ILP; per-block partial writes (no atomics).
__global__ __launch_bounds__(256) void k_visit(const unsigned short* __restrict__ E,
                                               const float* __restrict__ CVs,
                                               float* __restrict__ PV) {
  int c8 = blockIdx.x * 2048 + threadIdx.x * 8;
  int r0 = blockIdx.y * 64;
  float va[8];
#pragma unroll
  for (int j = 0; j < 8; ++j) va[j] = 0.f;
  for (int r = 0; r < 64; r += 4) {
    bf16x8 e0 = *(const bf16x8*)(E + (size_t)(r0 + r) * NROW + c8);
    bf16x8 e1 = *(const bf16x8*)(E + (size_t)(r0 + r + 1) * NROW + c8);
    bf16x8 e2 = *(const bf16x8*)(E + (size_t)(r0 + r + 2) * NROW + c8);
    bf16x8 e3 = *(const bf16x8*)(E + (size_t)(r0 + r + 3) * NROW + c8);
    float cv0 = CVs[r0 + r], cv1 = CVs[r0 + r + 1];
    float cv2 = CVs[r0 + r + 2], cv3 = CVs[r0 + r + 3];
#pragma unroll
    for (int j = 0; j < 8; ++j) {
      va[j] = fmaf(bf2f((unsigned short)e0[j]), cv0, va[j]);
      va[j] = fmaf(bf2f((unsigned short)e1[j]), cv1, va[j]);
      va[j] = fmaf(bf2f((unsigned short)e2[j]), cv2, va[j]);
      va[j] = fmaf(bf2f((unsigned short)e3[j]), cv3, va[j]);
    }
  }
  f32x4 w0 = {va[0], va[1], va[2], va[3]};
  f32x4 w1 = {va[4], va[5], va[6], va[7]};
  *(f32x4*)(PV + (size_t)blockIdx.y * NROW + c8) = w0;
  *(f32x4*)(PV + (size_t)blockIdx.y * NROW + c8 + 4) = w1;
}

__global__ __launch_bounds__(256) void k_vloss(const float* __restrict__ PV, double* va) {
  __shared__ float red[4];
  int tid = threadIdx.x;
  int i = blockIdx.x * 256 + tid;
  float v = 0.f;
  for (int t = 0; t < 128; ++t) v += PV[(size_t)t * NROW + i];
  float l = __logf(EPSf + v * (1.f / 8192.f));
#pragma unroll
  for (int off = 32; off; off >>= 1) l += __shfl_down(l, off);
  if ((tid & 63) == 0) red[tid >> 6] = l;
  __syncthreads();
  if (tid == 0) {
    double tot = (double)red[0] + (double)red[1] + (double)red[2] + (double)red[3];
    atomicAdd(va, -tot / 8192.0);
  }
}

// Per-label symmetric Gram on RAW E, split-K; ck folded into Rt staging.
// Tile pair (ti<=tj), 128x128, BK=64; xor-swizzled LDS; XCD-locality decode.
__global__ __launch_bounds__(256, 4) void k_gram(const unsigned short* __restrict__ Eh,
                                                 const int* __restrict__ cnt,
                                                 const int* __restrict__ offs,
                                                 const float* __restrict__ CKS,
                                                 unsigned short* __restrict__ Spart) {
  int gid = blockIdx.x;                // 0..1439
  int xcd = gid & 7, slot = gid >> 3;  // slot 0..179
  int group = xcd * 5 + slot / NPAIR;  // 0..39
  int pidx = slot % NPAIR;
  int lab = group / SPLIT, split = group % SPLIT;
  int tj = 0;
  while ((tj + 1) * (tj + 2) / 2 <= pidx) ++tj;
  int ti = pidx - tj * (tj + 1) / 2;
  int c = cnt[lab], o = offs[lab];
  if (tj * 128 >= c) return;
  __shared__ __align__(16) unsigned short Pt[128 * 64];
  __shared__ __align__(16) unsigned short Rt[128 * 64];
  int tid = threadIdx.x;
  int wave = tid >> 6, lane = tid & 63;
  int wrow = wave >> 1, wcol = wave & 1;
  int m = lane & 15, quad = lane >> 4;
  const unsigned short* pp[4];
  const unsigned short* pr[4];
  int lo[4];
#pragma unroll
  for (int v = 0; v < 4; ++v) {
    int slotv = v * 256 + tid, row = slotv >> 3, c8 = slotv & 7;
    int ri = o + ti * 128 + row; if (ri > NROW - 1) ri = NROW - 1;
    int rj = o + tj * 128 + row; if (rj > NROW - 1) rj = NROW - 1;
    pp[v] = Eh + (size_t)ri * NROW + split * 2048 + c8 * 8;
    pr[v] = Eh + (size_t)rj * NROW + split * 2048 + c8 * 8;
    lo[v] = row * 64 + ((c8 ^ (row & 7)) * 8);
  }
  // ck slice for this thread's column-set (c8 identical across v)
  const float* ckp = CKS + split * 2048 + (tid & 7) * 8;
  f32x4 acc[4][4];
#pragma unroll
  for (int mi = 0; mi < 4; ++mi)
#pragma unroll
    for (int ni = 0; ni < 4; ++ni) acc[mi][ni] = (f32x4){0.f, 0.f, 0.f, 0.f};
  for (int t = 0; t < 32; ++t) {
    __syncthreads();
    bf16x8 dp[4], dr[4];
#pragma unroll
    for (int v = 0; v < 4; ++v) {
      dp[v] = *(const bf16x8*)(pp[v]); pp[v] += 64;
      dr[v] = *(const bf16x8*)(pr[v]); pr[v] += 64;
    }
    f32x4 ck0 = *(const f32x4*)(ckp + t * 64);
    f32x4 ck1 = *(const f32x4*)(ckp + t * 64 + 4);
#pragma unroll
    for (int v = 0; v < 4; ++v) {
      *(bf16x8*)(Pt + lo[v]) = dp[v];
      float p0 = bf2f((unsigned short)dr[v][0]) * ck0[0];
      float p1 = bf2f((unsigned short)dr[v][1]) * ck0[1];
      float p2 = bf2f((unsigned short)dr[v][2]) * ck0[2];
      float p3 = bf2f((unsigned short)dr[v][3]) * ck0[3];
      float p4 = bf2f((unsigned short)dr[v][4]) * ck1[0];
      float p5 = bf2f((unsigned short)dr[v][5]) * ck1[1];
      float p6 = bf2f((unsigned short)dr[v][6]) * ck1[2];
      float p7 = bf2f((unsigned short)dr[v][7]) * ck1[3];
      uint4 q;
      q.x = pack2bf(p0, p1); q.y = pack2bf(p2, p3);
      q.z = pack2bf(p4, p5); q.w = pack2bf(p6, p7);
      *(uint4*)(Rt + lo[v]) = q;
    }
    __syncthreads();
#pragma unroll
    for (int ks = 0; ks < 2; ++ks) {
      bf16x8 pa[4], rb[4];
#pragma unroll
      for (int mi = 0; mi < 4; ++mi) {
        int row = wrow * 64 + mi * 16 + m;
        pa[mi] = *(const bf16x8*)(Pt + row * 64 + (((ks * 4 + quad) ^ (row & 7)) * 8));
      }
#pragma unroll
      for (int ni = 0; ni < 4; ++ni) {
        int row = wcol * 64 + ni * 16 + m;
        rb[ni] = *(const bf16x8*)(Rt + row * 64 + (((ks * 4 + quad) ^ (row & 7)) * 8));
      }
#pragma unroll
      for (int mi = 0; mi < 4; ++mi)
#pragma unroll
        for (int ni = 0; ni < 4; ++ni)
          acc[mi][ni] = __builtin_amdgcn_mfma_f32_16x16x32_bf16(pa[mi], rb[ni], acc[mi][ni], 0, 0, 0);
    }
  }
  // layout: base + (mi*4+ni)*1024 + tid*4 + r  (ushort4-packed stores)
  size_t base = (size_t)(split * SPSTRIDE) + (size_t)(lab * NPAIR + pidx) * 16384;
#pragma unroll
  for (int mi = 0; mi < 4; ++mi)
#pragma unroll
    for (int ni = 0; ni < 4; ++ni) {
      ushort4 w4;
      w4.x = f2bf(acc[mi][ni][0]);
      w4.y = f2bf(acc[mi][ni][1]);
      w4.z = f2bf(acc[mi][ni][2]);
      w4.w = f2bf(acc[mi][ni][3]);
      *(ushort4*)(Spart + base + (size_t)(mi * 4 + ni) * 1024 + tid * 4) = w4;
    }
}

// Sum split partials, apply log(eps + S * ISE), accumulate walker loss.
__global__ __launch_bounds__(256) void k_reduce(const unsigned short* __restrict__ Spart,
                                                const int* __restrict__ cnt,
                                                const int* __restrict__ offs,
                                                const float* __restrict__ CVs,
                                                double* wa) {
  int lab = blockIdx.y, pidx = blockIdx.x;
  int tj = 0;
  while ((tj + 1) * (tj + 2) / 2 <= pidx) ++tj;
  int ti = pidx - tj * (tj + 1) / 2;
  int c = cnt[lab], o = offs[lab];
  if (tj * 128 >= c) return;
  __shared__ float isei[128], isej[128];
  __shared__ float red[4];
  int tid = threadIdx.x;
  if (tid < 128) {
    int ri = o + ti * 128 + tid; if (ri > NROW - 1) ri = NROW - 1;
    int rj = o + tj * 128 + tid; if (rj > NROW - 1) rj = NROW - 1;
    isei[tid] = CVs[ri];
    isej[tid] = CVs[rj];
  }
  __syncthreads();
  int wave = tid >> 6, lane = tid & 63;
  int wrow = wave >> 1, wcol = wave & 1;
  int m = lane & 15, quad = lane >> 4;
  size_t base = (size_t)(lab * NPAIR + pidx) * 16384;
  float lsum = 0.f;
#pragma unroll
  for (int mi = 0; mi < 4; ++mi)
#pragma unroll
    for (int ni = 0; ni < 4; ++ni) {
      size_t off = base + (size_t)(mi * 4 + ni) * 1024 + tid * 4;
      ushort4 s0 = *(const ushort4*)(Spart + off);
      ushort4 s1 = *(const ushort4*)(Spart + SPSTRIDE + off);
      ushort4 s2 = *(const ushort4*)(Spart + 2 * (size_t)SPSTRIDE + off);
      ushort4 s3 = *(const ushort4*)(Spart + 3 * (size_t)SPSTRIDE + off);
      float S[4];
      S[0] = bf2f(s0.x) + bf2f(s1.x) + bf2f(s2.x) + bf2f(s3.x);
      S[1] = bf2f(s0.y) + bf2f(s1.y) + bf2f(s2.y) + bf2f(s3.y);
      S[2] = bf2f(s0.z) + bf2f(s1.z) + bf2f(s2.z) + bf2f(s3.z);
      S[3] = bf2f(s0.w) + bf2f(s1.w) + bf2f(s2.w) + bf2f(s3.w);
      int jl = wcol * 64 + ni * 16 + m;
      int j = tj * 128 + jl;
#pragma unroll
      for (int r = 0; r < 4; ++r) {
        int il = wrow * 64 + mi * 16 + quad * 4 + r;
        int i = ti * 128 + il;
        if (i < c && j < c) {
          lsum += __logf(EPSf + S[r] * isei[il]);
          if (ti != tj) lsum += __logf(EPSf + S[r] * isej[jl]);
        }
      }
    }
#pragma unroll
  for (int off2 = 32; off2; off2 >>= 1) lsum += __shfl_down(lsum, off2);
  if (lane == 0) red[wave] = lsum;
  __syncthreads();
  if (tid == 0) {
    double tot = (double)red[0] + (double)red[1] + (double)red[2] + (double)red[3];
    atomicAdd(wa, -tot / (8192.0 * (double)c));
  }
}

__global__ void k_finish(const double* wa, const double* va, float* out) {
  out[0] = (float)(*wa);
  out[1] = (float)(*va);
}

extern "C" void kernel_launch(void* const* d_in, const int* in_sizes, int n_in,
                              void* d_out, int out_size, void* d_ws, size_t ws_size,
                              hipStream_t stream) {
  const float* A = (const float*)d_in[0];
  const float* B = (const float*)d_in[1];
  const int* LAB = (const int*)d_in[2];
  float* out = (float*)d_out;
  char* w = (char*)d_ws;
  double* WA = (double*)(w + O_WA);
  double* VA = (double*)(w + O_VA);
  int* CNT = (int*)(w + O_CNT);
  int* OFFS = (int*)(w + O_OFF);
  int* SIDX = (int*)(w + O_SIDX);
  float* PS = (float*)(w + O_PS);
  float* CS = (float*)(w + O_CS);
  float* CVs = (float*)(w + O_CV);
  float* CKS = (float*)(w + O_CKS);
  unsigned short* ABF = (unsigned short*)(w + O_ABF);
  unsigned short* BBF = (unsigned short*)(w + O_BBF);
  unsigned short* E = (unsigned short*)(w + O_E);
  unsigned short* SP = (unsigned short*)(w + O_SP);
  float* PV = (float*)(w + O_PV);

  k_bucket<<<1, 256, 0, stream>>>(LAB, CNT, OFFS, SIDX, WA, VA, CS);
  k_convert<<<512, 256, 0, stream>>>(A, ABF);
  k_convert<<<512, 256, 0, stream>>>(B, BBF);
  k_score<<<dim3(64, 8), 256, 0, stream>>>(ABF, BBF, SIDX, E, PS, CS);
  k_mstats<<<32, 256, 0, stream>>>(PS, CS, CVs, CKS);
  k_visit<<<dim3(4, 128), 256, 0, stream>>>(E, CVs, PV);
  k_vloss<<<32, 256, 0, stream>>>(PV, VA);
  k_gram<<<NPAIR * SPLIT * NLAB, 256, 0, stream>>>(E, CNT, OFFS, CKS, SP);
  k_reduce<<<dim3(NPAIR, NLAB), 256, 0, stream>>>(SP, CNT, OFFS, CVs, WA);
  k_finish<<<1, 1, 0, stream>>>(WA, VA, out);
}

// Round 7
// 300.052 us; speedup vs baseline: 11.2263x; 1.0132x over previous
//
#include <hip/hip_runtime.h>

// WalkerVisitLosses, round 7.
// E = exp2(A'.B'^T) (A'=A*SF, SF^2=log2(e)/sqrt(128)); SE_i row sums,
// CS_k col sums. Ehat = E*rsqrt(CS) -> S = Ehat.Ehat^T symmetric;
// walker from log(eps + S/SE_i) on same-label tile pairs;
// visit_k = sum_p E_pk/SE_p.
// Round-7 deltas: two-GEMM-pass structure. k_stats computes SE/CS with NO
// stores; k_fill recomputes E, writes Ehat directly (scale known) and
// accumulates raw visit atomically. k_visit eliminated; k_gram staging is a
// pure copy on both operands (no repack VALU).

typedef __attribute__((ext_vector_type(8))) short bf16x8;
typedef __attribute__((ext_vector_type(4))) float f32x4;

#define NROW 8192
#define DIM 128
#define NLAB 10
#define EPSf 1e-8f
#define SF 0.35709582f /* sqrt( log2(e)/sqrt(128) ) */
#define SPLIT 4
#define NPAIR 36   /* supports up to 8 row-tiles per label */
#define SPSTRIDE (360 * 16384) /* elements per split */

// workspace byte offsets (total ~186.3 MB)
#define O_WA 0
#define O_VA 8
#define O_CNT 64
#define O_OFF 128
#define O_SIDX 256
#define O_PS 33280
#define O_CS 557568
#define O_VK 590336
#define O_CV 623104
#define O_CKS 655872
#define O_ABF 688640
#define O_BBF 2785792
#define O_E 4882944
#define O_SP 139100672

__device__ __forceinline__ unsigned short f2bf(float f) {
  unsigned u = __builtin_bit_cast(unsigned, f);
  u += 0x7fffu + ((u >> 16) & 1u);
  return (unsigned short)(u >> 16);
}
__device__ __forceinline__ float bf2f(unsigned short s) {
  unsigned u = ((unsigned)s) << 16;
  return __builtin_bit_cast(float, u);
}

__global__ __launch_bounds__(256) void k_bucket(const int* __restrict__ lab,
                                                int* cnt, int* offs, int* sidx,
                                                double* wa, double* va,
                                                float* cs, float* vk) {
  __shared__ int lc[NLAB], lcur[NLAB];
  int tid = threadIdx.x;
  if (tid < NLAB) lc[tid] = 0;
  __syncthreads();
  for (int i = tid; i < NROW; i += 256) {
    int l = lab[i]; l = l < 0 ? 0 : (l > 9 ? 9 : l);
    atomicAdd(&lc[l], 1);
  }
  for (int i = tid; i < NROW; i += 256) { cs[i] = 0.f; vk[i] = 0.f; }
  __syncthreads();
  if (tid == 0) {
    int run = 0;
    for (int l = 0; l < NLAB; ++l) { cnt[l] = lc[l]; offs[l] = run; lcur[l] = run; run += lc[l]; }
    *wa = 0.0; *va = 0.0;
  }
  __syncthreads();
  for (int i = tid; i < NROW; i += 256) {
    int l = lab[i]; l = l < 0 ? 0 : (l > 9 ? 9 : l);
    int p = atomicAdd(&lcur[l], 1);
    sidx[p] = i;
  }
}

__global__ __launch_bounds__(256) void k_convert(const float* __restrict__ X,
                                                 unsigned short* __restrict__ Y) {
  int i = (blockIdx.x * 256 + threadIdx.x) * 8;
  f32x4 a = *(const f32x4*)(X + i);
  f32x4 b = *(const f32x4*)(X + i + 4);
  bf16x8 o;
  o[0] = (short)f2bf(a[0] * SF); o[1] = (short)f2bf(a[1] * SF);
  o[2] = (short)f2bf(a[2] * SF); o[3] = (short)f2bf(a[3] * SF);
  o[4] = (short)f2bf(b[0] * SF); o[5] = (short)f2bf(b[1] * SF);
  o[6] = (short)f2bf(b[2] * SF); o[7] = (short)f2bf(b[3] * SF);
  *(bf16x8*)(Y + i) = o;
}

// Pass 1: GEMM+exp only -> row partial sums (ps) + col sums (atomic CS).
// NO E stores. Rows in sorted order (gidx gather).
__global__ __launch_bounds__(256, 2) void k_stats(const unsigned short* __restrict__ Abf,
                                                  const unsigned short* __restrict__ Bbf,
                                                  const int* __restrict__ sidx,
                                                  float* __restrict__ ps,
                                                  float* __restrict__ CS) {
  __shared__ int gidx[128];
  int tid = threadIdx.x;
  if (tid < 128) gidx[tid] = sidx[blockIdx.x * 128 + tid];
  __syncthreads();
  int wave = tid >> 6, lane = tid & 63;
  int wrow = wave >> 1, wcol = wave & 1;
  int m = lane & 15, quad = lane >> 4;
  bf16x8 af[4][4];
#pragma unroll
  for (int mi = 0; mi < 4; ++mi) {
    int gi = gidx[wrow * 64 + mi * 16 + m];
#pragma unroll
    for (int ks = 0; ks < 4; ++ks)
      af[mi][ks] = *(const bf16x8*)(Abf + gi * DIM + ks * 32 + quad * 8);
  }
  float tsum[4][4];
#pragma unroll
  for (int mi = 0; mi < 4; ++mi)
#pragma unroll
    for (int r = 0; r < 4; ++r) tsum[mi][r] = 0.f;
  int p0 = blockIdx.x * 128 + wrow * 64;
  for (int t = 0; t < 8; ++t) {
    int c0 = blockIdx.y * 1024 + t * 128 + wcol * 64;
    bf16x8 bfr[4][4];
#pragma unroll
    for (int ni = 0; ni < 4; ++ni)
#pragma unroll
      for (int ks = 0; ks < 4; ++ks)
        bfr[ni][ks] = *(const bf16x8*)(Bbf + (c0 + ni * 16 + m) * DIM + ks * 32 + quad * 8);
    f32x4 acc[4][4];
#pragma unroll
    for (int mi = 0; mi < 4; ++mi)
#pragma unroll
      for (int ni = 0; ni < 4; ++ni) acc[mi][ni] = (f32x4){0.f, 0.f, 0.f, 0.f};
#pragma unroll
    for (int ks = 0; ks < 4; ++ks)
#pragma unroll
      for (int mi = 0; mi < 4; ++mi)
#pragma unroll
        for (int ni = 0; ni < 4; ++ni)
          acc[mi][ni] = __builtin_amdgcn_mfma_f32_16x16x32_bf16(af[mi][ks], bfr[ni][ks], acc[mi][ni], 0, 0, 0);
    float csum[4] = {0.f, 0.f, 0.f, 0.f};
#pragma unroll
    for (int mi = 0; mi < 4; ++mi)
#pragma unroll
      for (int ni = 0; ni < 4; ++ni)
#pragma unroll
        for (int r = 0; r < 4; ++r) {
          float e = __builtin_amdgcn_exp2f(acc[mi][ni][r]);
          tsum[mi][r] += e;
          csum[ni] += e;
        }
#pragma unroll
    for (int ni = 0; ni < 4; ++ni) {
      csum[ni] += __shfl_xor(csum[ni], 16);
      csum[ni] += __shfl_xor(csum[ni], 32);
    }
    if (lane < 16) {
#pragma unroll
      for (int ni = 0; ni < 4; ++ni) atomicAdd(&CS[c0 + ni * 16 + lane], csum[ni]);
    }
  }
#pragma unroll
  for (int off = 1; off < 16; off <<= 1)
#pragma unroll
    for (int mi = 0; mi < 4; ++mi)
#pragma unroll
      for (int r = 0; r < 4; ++r) tsum[mi][r] += __shfl_xor(tsum[mi][r], off);
  if (m == 0) {
#pragma unroll
    for (int mi = 0; mi < 4; ++mi)
#pragma unroll
      for (int r = 0; r < 4; ++r)
        ps[(blockIdx.y * 2 + wcol) * NROW + p0 + mi * 16 + quad * 4 + r] = tsum[mi][r];
  }
}

__global__ __launch_bounds__(256) void k_mstats(const float* __restrict__ ps,
                                                const float* __restrict__ CS,
                                                float* __restrict__ CVs,
                                                float* __restrict__ CKS) {
  int i = blockIdx.x * 256 + threadIdx.x;
  float s = 0.f;
#pragma unroll
  for (int t = 0; t < 16; ++t) s += ps[t * NROW + i];
  CVs[i] = 1.f / s;
  CKS[i] = rsqrtf(CS[i]);
}

// Pass 2: recompute GEMM+exp, write Ehat = E*rsqrt(CS) in bf16 (sorted rows),
// accumulate raw visit VK[k] += E*CV[row] (atomic, col-reduced per wave).
__global__ __launch_bounds__(256, 2) void k_fill(const unsigned short* __restrict__ Abf,
                                                 const unsigned short* __restrict__ Bbf,
                                                 const int* __restrict__ sidx,
                                                 const float* __restrict__ CVs,
                                                 const float* __restrict__ CKS,
                                                 unsigned short* __restrict__ E,
                                                 float* __restrict__ VK) {
  __shared__ int gidx[128];
  int tid = threadIdx.x;
  if (tid < 128) gidx[tid] = sidx[blockIdx.x * 128 + tid];
  __syncthreads();
  int wave = tid >> 6, lane = tid & 63;
  int wrow = wave >> 1, wcol = wave & 1;
  int m = lane & 15, quad = lane >> 4;
  int p0 = blockIdx.x * 128 + wrow * 64;
  bf16x8 af[4][4];
  float cv16[4][4];
#pragma unroll
  for (int mi = 0; mi < 4; ++mi) {
    int gi = gidx[wrow * 64 + mi * 16 + m];
#pragma unroll
    for (int ks = 0; ks < 4; ++ks)
      af[mi][ks] = *(const bf16x8*)(Abf + gi * DIM + ks * 32 + quad * 8);
#pragma unroll
    for (int r = 0; r < 4; ++r) cv16[mi][r] = CVs[p0 + mi * 16 + quad * 4 + r];
  }
  for (int t = 0; t < 8; ++t) {
    int c0 = blockIdx.y * 1024 + t * 128 + wcol * 64;
    bf16x8 bfr[4][4];
    float ck4[4];
#pragma unroll
    for (int ni = 0; ni < 4; ++ni) {
      ck4[ni] = CKS[c0 + ni * 16 + m];
#pragma unroll
      for (int ks = 0; ks < 4; ++ks)
        bfr[ni][ks] = *(const bf16x8*)(Bbf + (c0 + ni * 16 + m) * DIM + ks * 32 + quad * 8);
    }
    f32x4 acc[4][4];
#pragma unroll
    for (int mi = 0; mi < 4; ++mi)
#pragma unroll
      for (int ni = 0; ni < 4; ++ni) acc[mi][ni] = (f32x4){0.f, 0.f, 0.f, 0.f};
#pragma unroll
    for (int ks = 0; ks < 4; ++ks)
#pragma unroll
      for (int mi = 0; mi < 4; ++mi)
#pragma unroll
        for (int ni = 0; ni < 4; ++ni)
          acc[mi][ni] = __builtin_amdgcn_mfma_f32_16x16x32_bf16(af[mi][ks], bfr[ni][ks], acc[mi][ni], 0, 0, 0);
    float csum[4] = {0.f, 0.f, 0.f, 0.f};
#pragma unroll
    for (int mi = 0; mi < 4; ++mi)
#pragma unroll
      for (int ni = 0; ni < 4; ++ni)
#pragma unroll
        for (int r = 0; r < 4; ++r) {
          float e = __builtin_amdgcn_exp2f(acc[mi][ni][r]);
          int row = p0 + mi * 16 + quad * 4 + r;
          E[(size_t)row * NROW + c0 + ni * 16 + m] = f2bf(e * ck4[ni]);
          csum[ni] = fmaf(e, cv16[mi][r], csum[ni]);
        }
#pragma unroll
    for (int ni = 0; ni < 4; ++ni) {
      csum[ni] += __shfl_xor(csum[ni], 16);
      csum[ni] += __shfl_xor(csum[ni], 32);
    }
    if (lane < 16) {
#pragma unroll
      for (int ni = 0; ni < 4; ++ni) atomicAdd(&VK[c0 + ni * 16 + lane], csum[ni]);
    }
  }
}

__global__ __launch_bounds__(256) void k_vloss(const float* __restrict__ VK, double* va) {
  __shared__ float red[4];
  int tid = threadIdx.x;
  int i = blockIdx.x * 256 + tid;
  float l = __logf(EPSf + VK[i] * (1.f / 8192.f));
#pragma unroll
  for (int off = 32; off; off >>= 1) l += __shfl_down(l, off);
  if ((tid & 63) == 0) red[tid >> 6] = l;
  __syncthreads();
  if (tid == 0) {
    double tot = (double)red[0] + (double)red[1] + (double)red[2] + (double)red[3];
    atomicAdd(va, -tot / 8192.0);
  }
}

// Per-label symmetric Gram on Ehat, split-K. Tile pair (ti<=tj), 128x128,
// BK=64; PURE-COPY xor-swizzled LDS staging; XCD-locality decode.
__global__ __launch_bounds__(256, 4) void k_gram(const unsigned short* __restrict__ Eh,
                                                 const int* __restrict__ cnt,
                                                 const int* __restrict__ offs,
                                                 unsigned short* __restrict__ Spart) {
  int gid = blockIdx.x;                // 0..1439
  int xcd = gid & 7, slot = gid >> 3;  // slot 0..179
  int group = xcd * 5 + slot / NPAIR;  // 0..39
  int pidx = slot % NPAIR;
  int lab = group / SPLIT, split = group % SPLIT;
  int tj = 0;
  while ((tj + 1) * (tj + 2) / 2 <= pidx) ++tj;
  int ti = pidx - tj * (tj + 1) / 2;
  int c = cnt[lab], o = offs[lab];
  if (tj * 128 >= c) return;
  const bool diag = (ti == tj);
  __shared__ __align__(16) unsigned short Pt[128 * 64];
  __shared__ __align__(16) unsigned short Rt[128 * 64];
  int tid = threadIdx.x;
  int wave = tid >> 6, lane = tid & 63;
  int wrow = wave >> 1, wcol = wave & 1;
  int m = lane & 15, quad = lane >> 4;
  const unsigned short* pp[4];
  const unsigned short* pr[4];
  int lo[4];
#pragma unroll
  for (int v = 0; v < 4; ++v) {
    int slotv = v * 256 + tid, row = slotv >> 3, c8 = slotv & 7;
    int ri = o + ti * 128 + row; if (ri > NROW - 1) ri = NROW - 1;
    int rj = o + tj * 128 + row; if (rj > NROW - 1) rj = NROW - 1;
    pp[v] = Eh + (size_t)ri * NROW + split * 2048 + c8 * 8;
    pr[v] = Eh + (size_t)rj * NROW + split * 2048 + c8 * 8;
    lo[v] = row * 64 + ((c8 ^ (row & 7)) * 8);
  }
  f32x4 acc[4][4];
#pragma unroll
  for (int mi = 0; mi < 4; ++mi)
#pragma unroll
    for (int ni = 0; ni < 4; ++ni) acc[mi][ni] = (f32x4){0.f, 0.f, 0.f, 0.f};
  const unsigned short* Bt = diag ? Pt : Rt;
  for (int t = 0; t < 32; ++t) {
    __syncthreads();
    bf16x8 dp[4], dr[4];
#pragma unroll
    for (int v = 0; v < 4; ++v) {
      dp[v] = *(const bf16x8*)(pp[v]); pp[v] += 64;
      if (!diag) { dr[v] = *(const bf16x8*)(pr[v]); pr[v] += 64; }
    }
#pragma unroll
    for (int v = 0; v < 4; ++v) {
      *(bf16x8*)(Pt + lo[v]) = dp[v];
      if (!diag) *(bf16x8*)(Rt + lo[v]) = dr[v];
    }
    __syncthreads();
#pragma unroll
    for (int ks = 0; ks < 2; ++ks) {
      bf16x8 pa[4], rb[4];
#pragma unroll
      for (int mi = 0; mi < 4; ++mi) {
        int row = wrow * 64 + mi * 16 + m;
        pa[mi] = *(const bf16x8*)(Pt + row * 64 + (((ks * 4 + quad) ^ (row & 7)) * 8));
      }
#pragma unroll
      for (int ni = 0; ni < 4; ++ni) {
        int row = wcol * 64 + ni * 16 + m;
        rb[ni] = *(const bf16x8*)(Bt + row * 64 + (((ks * 4 + quad) ^ (row & 7)) * 8));
      }
#pragma unroll
      for (int mi = 0; mi < 4; ++mi)
#pragma unroll
        for (int ni = 0; ni < 4; ++ni)
          acc[mi][ni] = __builtin_amdgcn_mfma_f32_16x16x32_bf16(pa[mi], rb[ni], acc[mi][ni], 0, 0, 0);
    }
  }
  // layout: base + (mi*4+ni)*1024 + tid*4 + r  (ushort4-packed stores)
  size_t base = (size_t)(split * SPSTRIDE) + (size_t)(lab * NPAIR + pidx) * 16384;
#pragma unroll
  for (int mi = 0; mi < 4; ++mi)
#pragma unroll
    for (int ni = 0; ni < 4; ++ni) {
      ushort4 w4;
      w4.x = f2bf(acc[mi][ni][0]);
      w4.y = f2bf(acc[mi][ni][1]);
      w4.z = f2bf(acc[mi][ni][2]);
      w4.w = f2bf(acc[mi][ni][3]);
      *(ushort4*)(Spart + base + (size_t)(mi * 4 + ni) * 1024 + tid * 4) = w4;
    }
}

// Sum split partials, apply log(eps + S * ISE), accumulate walker loss.
__global__ __launch_bounds__(256) void k_reduce(const unsigned short* __restrict__ Spart,
                                                const int* __restrict__ cnt,
                                                const int* __restrict__ offs,
                                                const float* __restrict__ CVs,
                                                double* wa) {
  int lab = blockIdx.y, pidx = blockIdx.x;
  int tj = 0;
  while ((tj + 1) * (tj + 2) / 2 <= pidx) ++tj;
  int ti = pidx - tj * (tj + 1) / 2;
  int c = cnt[lab], o = offs[lab];
  if (tj * 128 >= c) return;
  __shared__ float isei[128], isej[128];
  __shared__ float red[4];
  int tid = threadIdx.x;
  if (tid < 128) {
    int ri = o + ti * 128 + tid; if (ri > NROW - 1) ri = NROW - 1;
    int rj = o + tj * 128 + tid; if (rj > NROW - 1) rj = NROW - 1;
    isei[tid] = CVs[ri];
    isej[tid] = CVs[rj];
  }
  __syncthreads();
  int wave = tid >> 6, lane = tid & 63;
  int wrow = wave >> 1, wcol = wave & 1;
  int m = lane & 15, quad = lane >> 4;
  size_t base = (size_t)(lab * NPAIR + pidx) * 16384;
  float lsum = 0.f;
#pragma unroll
  for (int mi = 0; mi < 4; ++mi)
#pragma unroll
    for (int ni = 0; ni < 4; ++ni) {
      size_t off = base + (size_t)(mi * 4 + ni) * 1024 + tid * 4;
      ushort4 s0 = *(const ushort4*)(Spart + off);
      ushort4 s1 = *(const ushort4*)(Spart + SPSTRIDE + off);
      ushort4 s2 = *(const ushort4*)(Spart + 2 * (size_t)SPSTRIDE + off);
      ushort4 s3 = *(const ushort4*)(Spart + 3 * (size_t)SPSTRIDE + off);
      float S[4];
      S[0] = bf2f(s0.x) + bf2f(s1.x) + bf2f(s2.x) + bf2f(s3.x);
      S[1] = bf2f(s0.y) + bf2f(s1.y) + bf2f(s2.y) + bf2f(s3.y);
      S[2] = bf2f(s0.z) + bf2f(s1.z) + bf2f(s2.z) + bf2f(s3.z);
      S[3] = bf2f(s0.w) + bf2f(s1.w) + bf2f(s2.w) + bf2f(s3.w);
      int jl = wcol * 64 + ni * 16 + m;
      int j = tj * 128 + jl;
#pragma unroll
      for (int r = 0; r < 4; ++r) {
        int il = wrow * 64 + mi * 16 + quad * 4 + r;
        int i = ti * 128 + il;
        if (i < c && j < c) {
          lsum += __logf(EPSf + S[r] * isei[il]);
          if (ti != tj) lsum += __logf(EPSf + S[r] * isej[jl]);
        }
      }
    }
#pragma unroll
  for (int off2 = 32; off2; off2 >>= 1) lsum += __shfl_down(lsum, off2);
  if (lane == 0) red[wave] = lsum;
  __syncthreads();
  if (tid == 0) {
    double tot = (double)red[0] + (double)red[1] + (double)red[2] + (double)red[3];
    atomicAdd(wa, -tot / (8192.0 * (double)c));
  }
}

__global__ void k_finish(const double* wa, const double* va, float* out) {
  out[0] = (float)(*wa);
  out[1] = (float)(*va);
}

extern "C" void kernel_launch(void* const* d_in, const int* in_sizes, int n_in,
                              void* d_out, int out_size, void* d_ws, size_t ws_size,
                              hipStream_t stream) {
  const float* A = (const float*)d_in[0];
  const float* B = (const float*)d_in[1];
  const int* LAB = (const int*)d_in[2];
  float* out = (float*)d_out;
  char* w = (char*)d_ws;
  double* WA = (double*)(w + O_WA);
  double* VA = (double*)(w + O_VA);
  int* CNT = (int*)(w + O_CNT);
  int* OFFS = (int*)(w + O_OFF);
  int* SIDX = (int*)(w + O_SIDX);
  float* PS = (float*)(w + O_PS);
  float* CS = (float*)(w + O_CS);
  float* VK = (float*)(w + O_VK);
  float* CVs = (float*)(w + O_CV);
  float* CKS = (float*)(w + O_CKS);
  unsigned short* ABF = (unsigned short*)(w + O_ABF);
  unsigned short* BBF = (unsigned short*)(w + O_BBF);
  unsigned short* E = (unsigned short*)(w + O_E);
  unsigned short* SP = (unsigned short*)(w + O_SP);

  k_bucket<<<1, 256, 0, stream>>>(LAB, CNT, OFFS, SIDX, WA, VA, CS, VK);
  k_convert<<<512, 256, 0, stream>>>(A, ABF);
  k_convert<<<512, 256, 0, stream>>>(B, BBF);
  k_stats<<<dim3(64, 8), 256, 0, stream>>>(ABF, BBF, SIDX, PS, CS);
  k_mstats<<<32, 256, 0, stream>>>(PS, CS, CVs, CKS);
  k_fill<<<dim3(64, 8), 256, 0, stream>>>(ABF, BBF, SIDX, CVs, CKS, E, VK);
  k_vloss<<<32, 256, 0, stream>>>(VK, VA);
  k_gram<<<NPAIR * SPLIT * NLAB, 256, 0, stream>>>(E, CNT, OFFS, SP);
  k_reduce<<<dim3(NPAIR, NLAB), 256, 0, stream>>>(SP, CNT, OFFS, CVs, WA);
  k_finish<<<1, 1, 0, stream>>>(WA, VA, out);
}